// Round 6
// baseline (807.806 us; speedup 1.0000x reference)
//
#include <hip/hip_runtime.h>
#include <math.h>

#define NBR 4
#define NLAY 3
#define Bk 4
#define Tk 1024
#define DIN 32
#define DMODEL 128
#define DINNER 256
#define DSTATE 16
#define DTRANK 8
#define EMBEDk 64
#define BT (Bk*Tk)          /* 4096 rows per branch */
#define EPSF 1e-7f
#define MAXNF 10.0f
#define LCH 64              /* scan chunk length */
#define NCH (Tk/LCH)        /* 16 chunks */
#define UF 8                /* t-loop batch (latency amortization) */
#define NWC 384             /* padded dt|bc weight panel width */

__device__ __forceinline__ float siluf(float x){ return x / (1.f + __expf(-x)); }
__device__ __forceinline__ float softplusf(float x){ return (x > 20.f) ? x : log1pf(__expf(x)); }

// dA[s] = q^(s+1) from q (A_s = -(s+1) fast path)
__device__ __forceinline__ void dA_pow(float q, float* dA){
    dA[0] = q;             dA[1] = q * q;
    dA[2] = dA[1] * dA[0]; dA[3] = dA[1] * dA[1];
    dA[4] = dA[3] * dA[0]; dA[5] = dA[3] * dA[1];
    dA[6] = dA[3] * dA[2]; dA[7] = dA[3] * dA[3];
    #pragma unroll
    for (int s = 8; s < 16; ++s) dA[s] = dA[s - 8] * dA[7];
}
// generic fallback: dA[s] = exp(dtv * Aa[s])
__device__ __forceinline__ void dA_exp(float dtv, const float* Aa, float* dA){
    #pragma unroll
    for (int s = 0; s < 16; ++s) dA[s] = __expf(dtv * Aa[s]);
}

// ---------------------------------------------------------------------------
// fp32 SGEMM: C = A(MxK) @ B(KxN), 128x128 tile, Kc=32, 8x8 per thread as a
// 2x2 grid of 4x4 sub-tiles (rows {ty*4, 64+ty*4}, cols {tx*4, 64+tx*4}) so
// every LDS fragment read is stride-4 float4 -> conflict-free (2 lanes/bank).
// MODE 0: xz  -> col<256: raw to C0 (xp); col>=256: silu to C1 (z)
// MODE 1: plain store to C0 (ldc)
// MODE 2: input proj -> +bias; A selected from {A,A1,A2,A3} by blockIdx.z
// MODE 3: dt|bc -> col<256: softplus(v+bias) to C0 (dt, ld 256);
//                  col 256..287 raw to C1 (bc, ld 32); col>=288 dropped
// M mult of 128, N mult of 128, K mult of 32.
// ---------------------------------------------------------------------------
template<int MODE>
__global__ __launch_bounds__(256) void sgemm2_k(
    const float* __restrict__ A,  const float* __restrict__ A1,
    const float* __restrict__ A2, const float* __restrict__ A3,
    int lda, long aBr,
    const float* __restrict__ Bw, int ldb, long bBr,
    float* __restrict__ C0, long cBr,
    float* __restrict__ C1, long c1Br, int ldc,
    const float* __restrict__ bias, long biasBr, int K)
{
    const int br = blockIdx.z;
    if (MODE == 2) {
        A = (br == 1) ? A1 : (br == 2) ? A2 : (br == 3) ? A3 : A;
    } else {
        A += (long)br * aBr;
    }
    Bw += (long)br * bBr;
    C0 += (long)br * cBr;
    if (MODE == 0 || MODE == 3) C1 += (long)br * c1Br;
    if (MODE == 2 || MODE == 3) bias += (long)br * biasBr;
    const int m0 = blockIdx.x * 128, n0 = blockIdx.y * 128;
    __shared__ float As[32][132];   // [k][m]
    __shared__ float Bs[32][132];   // [k][n]
    const int tid = threadIdx.x;
    const int tx = tid & 15, ty = tid >> 4;
    float acc[2][2][4][4] = {};     // [ih][jh][i][j]
    for (int kc = 0; kc < K; kc += 32) {
        #pragma unroll
        for (int it = 0; it < 4; ++it) {
            int id = tid + it * 256;
            int r = id >> 3, c4 = (id & 7) << 2;
            float4 v = *(const float4*)(A + (long)(m0 + r) * lda + kc + c4);
            As[c4+0][r] = v.x; As[c4+1][r] = v.y; As[c4+2][r] = v.z; As[c4+3][r] = v.w;
            int rb = id >> 5, cb = (id & 31) << 2;
            *(float4*)&Bs[rb][cb] = *(const float4*)(Bw + (long)(kc + rb) * ldb + n0 + cb);
        }
        __syncthreads();
        #pragma unroll
        for (int kk = 0; kk < 32; ++kk) {
            float a[8], b[8];
            *(float4*)&a[0] = *(const float4*)&As[kk][ty * 4];        // stride-4: free
            *(float4*)&a[4] = *(const float4*)&As[kk][64 + ty * 4];
            *(float4*)&b[0] = *(const float4*)&Bs[kk][tx * 4];
            *(float4*)&b[4] = *(const float4*)&Bs[kk][64 + tx * 4];
            #pragma unroll
            for (int ih = 0; ih < 2; ++ih)
                #pragma unroll
                for (int i = 0; i < 4; ++i)
                    #pragma unroll
                    for (int jh = 0; jh < 2; ++jh)
                        #pragma unroll
                        for (int j = 0; j < 4; ++j)
                            acc[ih][jh][i][j] =
                                fmaf(a[ih*4+i], b[jh*4+j], acc[ih][jh][i][j]);
        }
        __syncthreads();
    }
    #pragma unroll
    for (int ih = 0; ih < 2; ++ih) {
        #pragma unroll
        for (int i = 0; i < 4; ++i) {
            const int row = m0 + ih * 64 + ty * 4 + i;
            #pragma unroll
            for (int jh = 0; jh < 2; ++jh) {
                const int col = n0 + jh * 64 + tx * 4;
                float v[4];
                #pragma unroll
                for (int j = 0; j < 4; ++j) v[j] = acc[ih][jh][i][j];
                if (MODE == 2) {
                    #pragma unroll
                    for (int j = 0; j < 4; ++j) v[j] += bias[col + j];
                }
                if (MODE == 0 && col >= 256) {
                    #pragma unroll
                    for (int j = 0; j < 4; ++j) v[j] = siluf(v[j]);
                }
                if (MODE == 3 && col < 256) {
                    #pragma unroll
                    for (int j = 0; j < 4; ++j) v[j] = softplusf(v[j] + bias[col + j]);
                }
                float4 v4; v4.x = v[0]; v4.y = v[1]; v4.z = v[2]; v4.w = v[3];
                if (MODE == 0) {
                    float* dst = (col < 256) ? (C0 + (long)row * DINNER + col)
                                             : (C1 + (long)row * DINNER + (col - 256));
                    *(float4*)dst = v4;
                } else if (MODE == 1 || MODE == 2) {
                    *(float4*)(C0 + (long)row * ldc + col) = v4;
                } else {
                    if (col < 256) {
                        *(float4*)(C0 + (long)row * 256 + col) = v4;
                    } else if (col < 288) {
                        *(float4*)(C1 + (long)row * 32 + (col - 256)) = v4;
                    }
                }
            }
        }
    }
}

// ---------------------------------------------------------------------------
// prep: per (br, layer) build padded weight panel wc (256 x 384):
//   cols 0..255  = Wx[:, :8] @ Wdt   (so dt = softplus(xc @ wc[:, :256] + b_dt))
//   cols 256..287 = Wx[:, 8:40]      (B,C)
//   cols 288..383 = 0
// ---------------------------------------------------------------------------
__global__ __launch_bounds__(256) void prep_k(
    const float* __restrict__ Wx, const float* __restrict__ Wdt,
    float* __restrict__ wc, int layer)
{
    const int br = blockIdx.x, kq = blockIdx.y;
    const int j = threadIdx.x;
    const float* WxP  = Wx  + (long)(br * NLAY + layer) * DINNER * 40;
    const float* WdtP = Wdt + (long)(br * NLAY + layer) * DTRANK * DINNER;
    __shared__ float wxs[64][8];
    for (int idx = j; idx < 512; idx += 256) {
        int k = idx >> 3, r = idx & 7;
        wxs[k][r] = WxP[(long)(kq * 64 + k) * 40 + r];
    }
    float wdt[8];
    #pragma unroll
    for (int r = 0; r < 8; ++r) wdt[r] = WdtP[r * DINNER + j];
    __syncthreads();
    float* outp = wc + (long)br * (256 * NWC) + (long)kq * 64 * NWC;
    for (int k = 0; k < 64; ++k) {
        float acc = 0.f;
        #pragma unroll
        for (int r = 0; r < 8; ++r) acc = fmaf(wxs[k][r], wdt[r], acc);
        outp[k * NWC + j] = acc;
        if (j < 128) {
            int kg = kq * 64 + k;
            outp[k * NWC + 256 + j] = (j < 32) ? WxP[(long)kg * 40 + 8 + j] : 0.f;
        }
    }
}

// ---------------------------------------------------------------------------
// Depthwise causal conv (4 taps) + bias + silu.
// ---------------------------------------------------------------------------
__global__ __launch_bounds__(256) void conv_k(
    const float* __restrict__ xp, const float* __restrict__ cw,
    const float* __restrict__ cb, float* __restrict__ xc, int layer)
{
    const int br = blockIdx.y;
    const long base = (long)br * BT * DINNER;
    const int idx = blockIdx.x * 256 + threadIdx.x;
    const int d = idx & (DINNER - 1);
    const int row = idx >> 8;
    const int t = row & (Tk - 1);
    const float4 w4 = *(const float4*)(cw + ((long)(br * NLAY + layer) * DINNER + d) * 4);
    const float wv[4] = {w4.x, w4.y, w4.z, w4.w};
    float acc = cb[(br * NLAY + layer) * DINNER + d];
    const float* xpb = xp + base + idx;
    #pragma unroll
    for (int k = 0; k < 4; ++k) {
        int tt = t + k - 3;
        if (tt >= 0) acc = fmaf(xpb[(long)(k - 3) * DINNER], wv[k], acc);
    }
    xc[base + idx] = siluf(acc);
}

// ---------------------------------------------------------------------------
// Scan pass 1: per-chunk local recurrence from h=0 -> record (h_end[16], sumdt).
// ---------------------------------------------------------------------------
__global__ __launch_bounds__(256) void scan1_k(
    const float* __restrict__ dtb, const float* __restrict__ xcb,
    const float* __restrict__ bcb, const float* __restrict__ Alog,
    float* __restrict__ recbuf, int layer)
{
    const int c = blockIdx.x, b = blockIdx.y, br = blockIdx.z;
    const int d = threadIdx.x;
    const float* Ap = Alog + ((long)(br * NLAY + layer) * DINNER + d) * DSTATE;
    float Aa[16];
    bool pw = true;
    #pragma unroll
    for (int s = 0; s < 16; ++s) {
        Aa[s] = -__expf(Ap[s]);
        pw = pw && (fabsf(Aa[s] + (float)(s + 1)) < 1e-3f);
    }
    const long rbase = (long)br * BT + (long)b * Tk + (long)c * LCH;
    const float* dtp = dtb + rbase * DINNER + d;
    const float* xcp = xcb + rbase * DINNER + d;
    __shared__ float bcs[LCH * 32];      // 8 KB
    {
        const float4* g = (const float4*)(bcb + rbase * 32);
        float4* l = (float4*)bcs;
        l[d] = g[d]; l[d + 256] = g[d + 256];
    }
    float dtc[UF], xcc[UF];
    #pragma unroll
    for (int u = 0; u < UF; ++u) {
        dtc[u] = dtp[(long)u * DINNER];
        xcc[u] = xcp[(long)u * DINNER];
    }
    __syncthreads();
    float h[16];
    #pragma unroll
    for (int s = 0; s < 16; ++s) h[s] = 0.f;
    float sumdt = 0.f;
    for (int base = 0; base < LCH; base += UF) {
        const int nb = (base + UF < LCH) ? base + UF : base;
        float dtn[UF], xcn[UF];
        #pragma unroll
        for (int u = 0; u < UF; ++u) {
            dtn[u] = dtp[(long)(nb + u) * DINNER];
            xcn[u] = xcp[(long)(nb + u) * DINNER];
        }
        #pragma unroll
        for (int u = 0; u < UF; ++u) {
            const int t = base + u;
            const float dtv = dtc[u];
            const float dtxc = dtv * xcc[u];
            sumdt += dtv;
            float dA[16];
            if (pw) dA_pow(__expf(-dtv), dA);
            else    dA_exp(dtv, Aa, dA);
            const float* bcT = bcs + t * 32;     // uniform addr -> broadcast
            #pragma unroll
            for (int s = 0; s < 16; ++s)
                h[s] = fmaf(dA[s], h[s], dtxc * bcT[s]);
        }
        #pragma unroll
        for (int u = 0; u < UF; ++u) { dtc[u] = dtn[u]; xcc[u] = xcn[u]; }
    }
    float* sb = recbuf + (((long)(br * 4 + b) * (NCH - 1) + c) * 17) * 256 + d;
    #pragma unroll
    for (int s = 0; s < 16; ++s) sb[s * 256] = h[s];
    sb[16 * 256] = sumdt;
}

// ---------------------------------------------------------------------------
// Scan pass 2: sequential fold over chunk records -> chunk-start carries.
// ---------------------------------------------------------------------------
__global__ __launch_bounds__(256) void scan2_k(
    const float* __restrict__ Alog, const float* __restrict__ recbuf,
    float* __restrict__ carbuf, int layer)
{
    const int br = blockIdx.x >> 2, b = blockIdx.x & 3;
    const int d = threadIdx.x;
    const float* Ap = Alog + ((long)(br * NLAY + layer) * DINNER + d) * DSTATE;
    float Aa[16];
    bool pw = true;
    #pragma unroll
    for (int s = 0; s < 16; ++s) {
        Aa[s] = -__expf(Ap[s]);
        pw = pw && (fabsf(Aa[s] + (float)(s + 1)) < 1e-3f);
    }
    const float* recB = recbuf + ((long)(br * 4 + b) * (NCH - 1)) * 17 * 256 + d;
    float* carB = carbuf + ((long)(br * 4 + b) * NCH) * 16 * 256 + d;
    float h[16];
    #pragma unroll
    for (int s = 0; s < 16; ++s) h[s] = 0.f;
    float rh[16], rs;
    #pragma unroll
    for (int s = 0; s < 16; ++s) rh[s] = recB[s * 256];
    rs = recB[16 * 256];
    for (int c = 0; c < NCH; ++c) {
        float* car = carB + (long)c * 16 * 256;
        #pragma unroll
        for (int s = 0; s < 16; ++s) car[s * 256] = h[s];
        if (c < NCH - 1) {
            float nh[16], ns = 0.f;
            if (c + 1 < NCH - 1) {
                const float* r2 = recB + (long)(c + 1) * 17 * 256;
                #pragma unroll
                for (int s = 0; s < 16; ++s) nh[s] = r2[s * 256];
                ns = r2[16 * 256];
            } else {
                #pragma unroll
                for (int s = 0; s < 16; ++s) nh[s] = 0.f;
            }
            float P[16];
            if (pw) dA_pow(__expf(-rs), P);
            else    dA_exp(rs, Aa, P);
            #pragma unroll
            for (int s = 0; s < 16; ++s) h[s] = fmaf(h[s], P[s], rh[s]);
            #pragma unroll
            for (int s = 0; s < 16; ++s) rh[s] = nh[s];
            rs = ns;
        }
    }
}

// ---------------------------------------------------------------------------
// Scan pass 3: carry + local recurrence; yz = (y + Dp*xc)*silu(z).
// ---------------------------------------------------------------------------
__global__ __launch_bounds__(256) void scan3_k(
    const float* __restrict__ dtb, const float* __restrict__ xcb,
    const float* __restrict__ bcb, const float* __restrict__ zb,
    const float* __restrict__ Alog, const float* __restrict__ Dpar,
    const float* __restrict__ carbuf, float* __restrict__ yz, int layer)
{
    const int c = blockIdx.x, b = blockIdx.y, br = blockIdx.z;
    const int d = threadIdx.x;
    const float* car = carbuf + (((long)(br * 4 + b) * NCH + c) * 16) * 256 + d;
    float h[16];
    #pragma unroll
    for (int s = 0; s < 16; ++s) h[s] = car[s * 256];
    const float* Ap = Alog + ((long)(br * NLAY + layer) * DINNER + d) * DSTATE;
    float Aa[16];
    bool pw = true;
    #pragma unroll
    for (int s = 0; s < 16; ++s) {
        Aa[s] = -__expf(Ap[s]);
        pw = pw && (fabsf(Aa[s] + (float)(s + 1)) < 1e-3f);
    }
    const float Dp = Dpar[(br * NLAY + layer) * DINNER + d];
    const long rbase = (long)br * BT + (long)b * Tk + (long)c * LCH;
    const float* dtp = dtb + rbase * DINNER + d;
    const float* xcp = xcb + rbase * DINNER + d;
    const float* zp  = zb  + rbase * DINNER + d;
    float*       yp  = yz  + rbase * DINNER + d;
    __shared__ float bcs[LCH * 32];      // 8 KB
    {
        const float4* g = (const float4*)(bcb + rbase * 32);
        float4* l = (float4*)bcs;
        l[d] = g[d]; l[d + 256] = g[d + 256];
    }
    float dtc[UF], xcc[UF], zc[UF];
    #pragma unroll
    for (int u = 0; u < UF; ++u) {
        dtc[u] = dtp[(long)u * DINNER];
        xcc[u] = xcp[(long)u * DINNER];
        zc[u]  = zp[(long)u * DINNER];
    }
    __syncthreads();
    for (int base = 0; base < LCH; base += UF) {
        const int nb = (base + UF < LCH) ? base + UF : base;
        float dtn[UF], xcn[UF], zn[UF];
        #pragma unroll
        for (int u = 0; u < UF; ++u) {
            dtn[u] = dtp[(long)(nb + u) * DINNER];
            xcn[u] = xcp[(long)(nb + u) * DINNER];
            zn[u]  = zp[(long)(nb + u) * DINNER];
        }
        #pragma unroll
        for (int u = 0; u < UF; ++u) {
            const int t = base + u;
            const float dtv = dtc[u], xcv = xcc[u];
            const float dtxc = dtv * xcv;
            float dA[16];
            if (pw) dA_pow(__expf(-dtv), dA);
            else    dA_exp(dtv, Aa, dA);
            const float* bcT = bcs + t * 32;     // uniform addr -> broadcast
            #pragma unroll
            for (int s = 0; s < 16; ++s)
                h[s] = fmaf(dA[s], h[s], dtxc * bcT[s]);
            float y0 = 0.f, y1 = 0.f, y2 = 0.f, y3 = 0.f;
            #pragma unroll
            for (int s = 0; s < 16; s += 4) {
                y0 = fmaf(h[s+0], bcT[16+s+0], y0);
                y1 = fmaf(h[s+1], bcT[16+s+1], y1);
                y2 = fmaf(h[s+2], bcT[16+s+2], y2);
                y3 = fmaf(h[s+3], bcT[16+s+3], y3);
            }
            const float y = (y0 + y1) + (y2 + y3) + Dp * xcv;
            yp[(long)t * DINNER] = y * zc[u];
        }
        #pragma unroll
        for (int u = 0; u < UF; ++u) { dtc[u] = dtn[u]; xcc[u] = xcn[u]; zc[u] = zn[u]; }
    }
}

// ---------------------------------------------------------------------------
// mean over T then @ W_op + b_op -> z_t directly into d_out[0..1023].
// ---------------------------------------------------------------------------
__global__ __launch_bounds__(128) void meanop_k(
    const float* __restrict__ hbuf, const float* __restrict__ Wop,
    const float* __restrict__ bop, float* __restrict__ outzt)
{
    const int br = blockIdx.x >> 2, b = blockIdx.x & 3;
    const int tid = threadIdx.x;
    const float* hp = hbuf + ((long)br * BT + (long)b * Tk) * DMODEL + tid;
    float s = 0.f;
    for (int t = 0; t < Tk; ++t) s += hp[(long)t * DMODEL];
    __shared__ float hm[DMODEL];
    hm[tid] = s * (1.0f / Tk);
    __syncthreads();
    if (tid < EMBEDk) {
        float acc = bop[br * EMBEDk + tid];
        for (int k = 0; k < DMODEL; ++k)
            acc = fmaf(hm[k], Wop[(long)br * DMODEL * EMBEDk + k * EMBEDk + tid], acc);
        outzt[br * (Bk * EMBEDk) + b * EMBEDk + tid] = acc;
    }
}

// ---------------------------------------------------------------------------
// Lorentz epilogue.
// ---------------------------------------------------------------------------
__global__ __launch_bounds__(64) void final_k(
    const float* __restrict__ zt, float* __restrict__ out, const float* __restrict__ eff)
{
    const float es = tanhf(eff[0]);
    __shared__ float us[NBR][Bk][EMBEDk];
    const int t = threadIdx.x;
    if (t < 16) {
        const int br = t >> 2, b = t & 3;
        const float* z = zt + br * (Bk * EMBEDk) + b * EMBEDk;
        float n2 = 0.f;
        for (int e = 0; e < EMBEDk; ++e) { float v = z[e] * es; n2 = fmaf(v, v, n2); }
        const float n  = sqrtf(n2);
        const float nc = fminf(fmaxf(n, EPSF), MAXNF);
        const float sc = nc / fmaxf(n, EPSF);
        const float sh = sinhf(nc) / nc;
        const float fac = es * sc * sh;
        float* zh = out + 1024 + br * (Bk * (EMBEDk + 1)) + b * (EMBEDk + 1);
        float sp2 = 0.f;
        for (int e = 0; e < EMBEDk; ++e) {
            float spv = z[e] * fac;
            sp2 = fmaf(spv, spv, sp2);
            zh[1 + e] = spv;
            us[br][b][e] = spv;
        }
        const float t0 = sqrtf(1.f + sp2);
        zh[0] = t0;
        const float dd  = acoshf(fmaxf(t0, 1.f + EPSF));
        const float spn = fmaxf(sqrtf(sp2), EPSF);
        const float rr  = dd / spn;
        for (int e = 0; e < EMBEDk; ++e) us[br][b][e] *= rr;
    }
    __syncthreads();
    if (t < 4) {
        const int b = t;
        float ct[EMBEDk];
        float* cto = out + 2064 + b * EMBEDk;
        for (int e = 0; e < EMBEDk; ++e) {
            float v = us[0][b][e] + us[1][b][e] + us[2][b][e] + us[3][b][e];
            ct[e] = v; cto[e] = v;
        }
        float n2 = 0.f;
        for (int e = 0; e < EMBEDk; ++e) { float v = ct[e] * es; n2 = fmaf(v, v, n2); }
        const float n  = sqrtf(n2);
        const float nc = fminf(fmaxf(n, EPSF), MAXNF);
        const float sc = nc / fmaxf(n, EPSF);
        const float sh = sinhf(nc) / nc;
        const float fac = es * sc * sh;
        float* ch = out + 2320 + b * (EMBEDk + 1);
        float sp2 = 0.f;
        for (int e = 0; e < EMBEDk; ++e) {
            float spv = ct[e] * fac;
            sp2 = fmaf(spv, spv, sp2);
            ch[1 + e] = spv;
        }
        ch[0] = sqrtf(1.f + sp2);
    }
}

extern "C" void kernel_launch(void* const* d_in, const int* in_sizes, int n_in,
                              void* d_out, int out_size, void* d_ws, size_t ws_size,
                              hipStream_t stream)
{
    const float* X0 = (const float*)d_in[0];
    const float* X1 = (const float*)d_in[1];
    const float* X2 = (const float*)d_in[2];
    const float* X3 = (const float*)d_in[3];
    const float* W_ip   = (const float*)d_in[4];
    const float* b_ip   = (const float*)d_in[5];
    const float* W_in   = (const float*)d_in[6];
    const float* conv_w = (const float*)d_in[7];
    const float* conv_b = (const float*)d_in[8];
    const float* W_x    = (const float*)d_in[9];
    const float* W_dt   = (const float*)d_in[10];
    const float* b_dt   = (const float*)d_in[11];
    const float* A_log  = (const float*)d_in[12];
    const float* D_par  = (const float*)d_in[13];
    const float* W_out  = (const float*)d_in[14];
    const float* W_op   = (const float*)d_in[15];
    const float* b_op   = (const float*)d_in[16];
    const float* eff    = (const float*)d_in[17];
    float* out = (float*)d_out;
    float* ws  = (float*)d_ws;

    // workspace layout (floats), ~78 MB
    float* buf_h  = ws;                                  // 4*4096*128 = 2.097M
    float* buf_xp = buf_h  + (long)NBR * BT * DMODEL;    // 4*4096*256 (xp / wc panel / yz)
    float* buf_z  = buf_xp + (long)NBR * BT * DINNER;
    float* buf_xc = buf_z  + (long)NBR * BT * DINNER;
    float* buf_dt = buf_xc + (long)NBR * BT * DINNER;
    float* buf_bc = buf_dt + (long)NBR * BT * DINNER;    // 4*4096*32
    // scan records + carries alias buf_h (dead between xz-GEMM and W_out-GEMM)
    float* recbuf = buf_h;
    float* carbuf = buf_h + (long)16 * (NCH - 1) * 17 * 256;
    // dt|bc weight panel aliases buf_xp (xp dead after conv; yz written later)
    float* wcomb = buf_xp;

    // input projection, all branches in one dispatch: h0 = x @ W_ip + b_ip
    sgemm2_k<2><<<dim3(BT / 128, 1, NBR), 256, 0, stream>>>(
        X0, X1, X2, X3, DIN, 0,
        W_ip, DMODEL, (long)DIN * DMODEL,
        buf_h, (long)BT * DMODEL, nullptr, 0, DMODEL,
        b_ip, DMODEL, DIN);

    for (int l = 0; l < NLAY; ++l) {
        // xz = h @ W_in; split -> xp, silu(z)
        sgemm2_k<0><<<dim3(BT / 128, (2 * DINNER) / 128, NBR), 256, 0, stream>>>(
            buf_h, nullptr, nullptr, nullptr, DMODEL, (long)BT * DMODEL,
            W_in + (long)l * DMODEL * 2 * DINNER, 2 * DINNER,
            (long)NLAY * DMODEL * 2 * DINNER,
            buf_xp, (long)BT * DINNER, buf_z, (long)BT * DINNER, DINNER,
            nullptr, 0, DMODEL);
        // depthwise conv + silu
        conv_k<<<dim3((BT * DINNER) / 256, NBR), 256, 0, stream>>>(
            buf_xp, conv_w, conv_b, buf_xc, l);
        // build dt|bc weight panel (into buf_xp, xp now dead)
        prep_k<<<dim3(NBR, 4), 256, 0, stream>>>(W_x, W_dt, wcomb, l);
        // dt = softplus(xc @ wc[:,:256] + b_dt); bc = xc @ wc[:,256:288]
        sgemm2_k<3><<<dim3(BT / 128, NWC / 128, NBR), 256, 0, stream>>>(
            buf_xc, nullptr, nullptr, nullptr, DINNER, (long)BT * DINNER,
            wcomb, NWC, (long)256 * NWC,
            buf_dt, (long)BT * DINNER, buf_bc, (long)BT * 32, DINNER,
            b_dt + l * DINNER, (long)NLAY * DINNER, DINNER);
        // chunked scan: local records -> carry scan -> local w/ carry
        scan1_k<<<dim3(NCH - 1, Bk, NBR), 256, 0, stream>>>(
            buf_dt, buf_xc, buf_bc, A_log, recbuf, l);
        scan2_k<<<16, 256, 0, stream>>>(A_log, recbuf, carbuf, l);
        scan3_k<<<dim3(NCH, Bk, NBR), 256, 0, stream>>>(
            buf_dt, buf_xc, buf_bc, buf_z, A_log, D_par, carbuf, buf_xp, l);
        // h = yz @ W_out
        sgemm2_k<1><<<dim3(BT / 128, DMODEL / 128, NBR), 256, 0, stream>>>(
            buf_xp, nullptr, nullptr, nullptr, DINNER, (long)BT * DINNER,
            W_out + (long)l * DINNER * DMODEL, DMODEL,
            (long)NLAY * DINNER * DMODEL,
            buf_h, (long)BT * DMODEL, nullptr, 0, DMODEL,
            nullptr, 0, DINNER);
    }

    meanop_k<<<16, 128, 0, stream>>>(buf_h, W_op, b_op, out);
    final_k<<<1, 64, 0, stream>>>(out, out, eff);
}

// Round 7
// 670.338 us; speedup vs baseline: 1.2051x; 1.2051x over previous
//
#include <hip/hip_runtime.h>
#include <math.h>

#define NBR 4
#define NLAY 3
#define Bk 4
#define Tk 1024
#define DIN 32
#define DMODEL 128
#define DINNER 256
#define DSTATE 16
#define DTRANK 8
#define EMBEDk 64
#define BT (Bk*Tk)          /* 4096 rows per branch */
#define EPSF 1e-7f
#define MAXNF 10.0f
#define LCH 64              /* scan chunk length */
#define NCH (Tk/LCH)        /* 16 chunks */
#define UF 8                /* t-loop batch (latency amortization) */
#define NWC 320             /* dt|bc weight panel width: 256 dt + 32 bc + 32 pad */

__device__ __forceinline__ float siluf(float x){ return x / (1.f + __expf(-x)); }
__device__ __forceinline__ float softplusf(float x){ return (x > 20.f) ? x : log1pf(__expf(x)); }

// dA[s] = q^(s+1) from q (A_s = -(s+1) fast path)
__device__ __forceinline__ void dA_pow(float q, float* dA){
    dA[0] = q;             dA[1] = q * q;
    dA[2] = dA[1] * dA[0]; dA[3] = dA[1] * dA[1];
    dA[4] = dA[3] * dA[0]; dA[5] = dA[3] * dA[1];
    dA[6] = dA[3] * dA[2]; dA[7] = dA[3] * dA[3];
    #pragma unroll
    for (int s = 8; s < 16; ++s) dA[s] = dA[s - 8] * dA[7];
}
// generic fallback: dA[s] = exp(dtv * Aa[s])
__device__ __forceinline__ void dA_exp(float dtv, const float* Aa, float* dA){
    #pragma unroll
    for (int s = 0; s < 16; ++s) dA[s] = __expf(dtv * Aa[s]);
}

// ---------------------------------------------------------------------------
// fp32 SGEMM: C = A(MxK) @ B(KxN), 64x64 tile, Kc=32, 4x4 per thread.
// Proven conflict-free (rounds 1-4: SQ_LDS_BANK_CONFLICT = 0): fragment reads
// are stride-4 float4 (2 lanes/bank = free); grids are 512-2048 blocks ->
// 2-8 blocks/CU (occupancy), unlike the 128x128 variant (384 blocks, 11%).
// MODE 0: xz  -> col<256: raw to C0 (xp); col>=256: silu to C1 (z)
// MODE 1: plain store to C0 (ldc)
// MODE 2: input proj -> +bias; A selected from {A,A1,A2,A3} by blockIdx.z
// MODE 3: dt|bc -> col<256: softplus(v+bias) to C0 (dt, ld 256);
//                  col 256..287 raw to C1 (bc, ld 32); col>=288 dropped
// ---------------------------------------------------------------------------
template<int MODE>
__global__ __launch_bounds__(256) void sgemm_k(
    const float* __restrict__ A,  const float* __restrict__ A1,
    const float* __restrict__ A2, const float* __restrict__ A3,
    int lda, long aBr,
    const float* __restrict__ Bw, int ldb, long bBr,
    float* __restrict__ C0, long cBr,
    float* __restrict__ C1, long c1Br, int ldc,
    const float* __restrict__ bias, long biasBr, int K)
{
    const int br = blockIdx.z;
    if (MODE == 2) {
        A = (br == 1) ? A1 : (br == 2) ? A2 : (br == 3) ? A3 : A;
    } else {
        A += (long)br * aBr;
    }
    Bw += (long)br * bBr;
    C0 += (long)br * cBr;
    if (MODE == 0 || MODE == 3) C1 += (long)br * c1Br;
    if (MODE == 2 || MODE == 3) bias += (long)br * biasBr;
    const int m0 = blockIdx.x * 64, n0 = blockIdx.y * 64;
    __shared__ float As[32][68];
    __shared__ float Bs[32][68];
    const int tid = threadIdx.x;
    const int tx = tid & 15, ty = tid >> 4;
    float acc[4][4] = {};
    for (int kc = 0; kc < K; kc += 32) {
        #pragma unroll
        for (int it = 0; it < 2; ++it) {
            int id = tid + it * 256;
            int r = id >> 3, c4 = (id & 7) << 2;
            float4 v = *(const float4*)(A + (long)(m0 + r) * lda + kc + c4);
            As[c4+0][r] = v.x; As[c4+1][r] = v.y; As[c4+2][r] = v.z; As[c4+3][r] = v.w;
            int rb = id >> 4, cb = (id & 15) << 2;
            *(float4*)&Bs[rb][cb] = *(const float4*)(Bw + (long)(kc + rb) * ldb + n0 + cb);
        }
        __syncthreads();
        #pragma unroll
        for (int kk = 0; kk < 32; ++kk) {
            float4 a4 = *(const float4*)&As[kk][ty << 2];   // stride-4: conflict-free
            float4 b4 = *(const float4*)&Bs[kk][tx << 2];
            float av[4] = {a4.x, a4.y, a4.z, a4.w};
            float bv[4] = {b4.x, b4.y, b4.z, b4.w};
            #pragma unroll
            for (int i = 0; i < 4; ++i)
                #pragma unroll
                for (int j = 0; j < 4; ++j)
                    acc[i][j] = fmaf(av[i], bv[j], acc[i][j]);
        }
        __syncthreads();
    }
    const int col = n0 + (tx << 2);
    float bs[4] = {0.f, 0.f, 0.f, 0.f};
    if (MODE == 2 || (MODE == 3 && col < 256)) {
        #pragma unroll
        for (int j = 0; j < 4; ++j) bs[j] = bias[col + j];
    }
    #pragma unroll
    for (int i = 0; i < 4; ++i) {
        const int row = m0 + (ty << 2) + i;
        float v[4];
        #pragma unroll
        for (int j = 0; j < 4; ++j) v[j] = acc[i][j];
        if (MODE == 2) {
            #pragma unroll
            for (int j = 0; j < 4; ++j) v[j] += bs[j];
        }
        if (MODE == 0 && col >= 256) {
            #pragma unroll
            for (int j = 0; j < 4; ++j) v[j] = siluf(v[j]);
        }
        if (MODE == 3 && col < 256) {
            #pragma unroll
            for (int j = 0; j < 4; ++j) v[j] = softplusf(v[j] + bs[j]);
        }
        float4 v4; v4.x = v[0]; v4.y = v[1]; v4.z = v[2]; v4.w = v[3];
        if (MODE == 0) {
            float* dst = (col < 256) ? (C0 + (long)row * DINNER + col)
                                     : (C1 + (long)row * DINNER + (col - 256));
            *(float4*)dst = v4;
        } else if (MODE == 1 || MODE == 2) {
            *(float4*)(C0 + (long)row * ldc + col) = v4;
        } else {
            if (col < 256) {
                *(float4*)(C0 + (long)row * 256 + col) = v4;
            } else if (col < 288) {
                *(float4*)(C1 + (long)row * 32 + (col - 256)) = v4;
            }
        }
    }
}

// ---------------------------------------------------------------------------
// prep: per (br, layer) build padded weight panel wc (256 x 320):
//   cols 0..255  = Wx[:, :8] @ Wdt   (so dt = softplus(xc @ wc[:, :256] + b_dt))
//   cols 256..287 = Wx[:, 8:40]      (B,C);  cols 288..319 = 0
// ---------------------------------------------------------------------------
__global__ __launch_bounds__(256) void prep_k(
    const float* __restrict__ Wx, const float* __restrict__ Wdt,
    float* __restrict__ wc, int layer)
{
    const int br = blockIdx.x, kq = blockIdx.y;
    const int j = threadIdx.x;
    const float* WxP  = Wx  + (long)(br * NLAY + layer) * DINNER * 40;
    const float* WdtP = Wdt + (long)(br * NLAY + layer) * DTRANK * DINNER;
    __shared__ float wxs[64][8];
    for (int idx = j; idx < 512; idx += 256) {
        int k = idx >> 3, r = idx & 7;
        wxs[k][r] = WxP[(long)(kq * 64 + k) * 40 + r];
    }
    float wdt[8];
    #pragma unroll
    for (int r = 0; r < 8; ++r) wdt[r] = WdtP[r * DINNER + j];
    __syncthreads();
    float* outp = wc + (long)br * (256 * NWC) + (long)kq * 64 * NWC;
    for (int k = 0; k < 64; ++k) {
        float acc = 0.f;
        #pragma unroll
        for (int r = 0; r < 8; ++r) acc = fmaf(wxs[k][r], wdt[r], acc);
        outp[k * NWC + j] = acc;
        if (j < 64) {
            int kg = kq * 64 + k;
            outp[k * NWC + 256 + j] = (j < 32) ? WxP[(long)kg * 40 + 8 + j] : 0.f;
        }
    }
}

// ---------------------------------------------------------------------------
// Depthwise causal conv (4 taps) + bias + silu.
// ---------------------------------------------------------------------------
__global__ __launch_bounds__(256) void conv_k(
    const float* __restrict__ xp, const float* __restrict__ cw,
    const float* __restrict__ cb, float* __restrict__ xc, int layer)
{
    const int br = blockIdx.y;
    const long base = (long)br * BT * DINNER;
    const int idx = blockIdx.x * 256 + threadIdx.x;
    const int d = idx & (DINNER - 1);
    const int row = idx >> 8;
    const int t = row & (Tk - 1);
    const float4 w4 = *(const float4*)(cw + ((long)(br * NLAY + layer) * DINNER + d) * 4);
    const float wv[4] = {w4.x, w4.y, w4.z, w4.w};
    float acc = cb[(br * NLAY + layer) * DINNER + d];
    const float* xpb = xp + base + idx;
    #pragma unroll
    for (int k = 0; k < 4; ++k) {
        int tt = t + k - 3;
        if (tt >= 0) acc = fmaf(xpb[(long)(k - 3) * DINNER], wv[k], acc);
    }
    xc[base + idx] = siluf(acc);
}

// ---------------------------------------------------------------------------
// Scan pass 1: per-chunk local recurrence from h=0 -> record (h_end[16], sumdt).
// ---------------------------------------------------------------------------
__global__ __launch_bounds__(256) void scan1_k(
    const float* __restrict__ dtb, const float* __restrict__ xcb,
    const float* __restrict__ bcb, const float* __restrict__ Alog,
    float* __restrict__ recbuf, int layer)
{
    const int c = blockIdx.x, b = blockIdx.y, br = blockIdx.z;
    const int d = threadIdx.x;
    const float* Ap = Alog + ((long)(br * NLAY + layer) * DINNER + d) * DSTATE;
    float Aa[16];
    bool pw = true;
    #pragma unroll
    for (int s = 0; s < 16; ++s) {
        Aa[s] = -__expf(Ap[s]);
        pw = pw && (fabsf(Aa[s] + (float)(s + 1)) < 1e-3f);
    }
    const long rbase = (long)br * BT + (long)b * Tk + (long)c * LCH;
    const float* dtp = dtb + rbase * DINNER + d;
    const float* xcp = xcb + rbase * DINNER + d;
    __shared__ float bcs[LCH * 32];      // 8 KB
    {
        const float4* g = (const float4*)(bcb + rbase * 32);
        float4* l = (float4*)bcs;
        l[d] = g[d]; l[d + 256] = g[d + 256];
    }
    float dtc[UF], xcc[UF];
    #pragma unroll
    for (int u = 0; u < UF; ++u) {
        dtc[u] = dtp[(long)u * DINNER];
        xcc[u] = xcp[(long)u * DINNER];
    }
    __syncthreads();
    float h[16];
    #pragma unroll
    for (int s = 0; s < 16; ++s) h[s] = 0.f;
    float sumdt = 0.f;
    for (int base = 0; base < LCH; base += UF) {
        const int nb = (base + UF < LCH) ? base + UF : base;
        float dtn[UF], xcn[UF];
        #pragma unroll
        for (int u = 0; u < UF; ++u) {
            dtn[u] = dtp[(long)(nb + u) * DINNER];
            xcn[u] = xcp[(long)(nb + u) * DINNER];
        }
        #pragma unroll
        for (int u = 0; u < UF; ++u) {
            const int t = base + u;
            const float dtv = dtc[u];
            const float dtxc = dtv * xcc[u];
            sumdt += dtv;
            float dA[16];
            if (pw) dA_pow(__expf(-dtv), dA);
            else    dA_exp(dtv, Aa, dA);
            const float* bcT = bcs + t * 32;     // uniform addr -> broadcast
            #pragma unroll
            for (int s = 0; s < 16; ++s)
                h[s] = fmaf(dA[s], h[s], dtxc * bcT[s]);
        }
        #pragma unroll
        for (int u = 0; u < UF; ++u) { dtc[u] = dtn[u]; xcc[u] = xcn[u]; }
    }
    float* sb = recbuf + (((long)(br * 4 + b) * (NCH - 1) + c) * 17) * 256 + d;
    #pragma unroll
    for (int s = 0; s < 16; ++s) sb[s * 256] = h[s];
    sb[16 * 256] = sumdt;
}

// ---------------------------------------------------------------------------
// Scan pass 2: sequential fold over chunk records -> chunk-start carries.
// ---------------------------------------------------------------------------
__global__ __launch_bounds__(256) void scan2_k(
    const float* __restrict__ Alog, const float* __restrict__ recbuf,
    float* __restrict__ carbuf, int layer)
{
    const int br = blockIdx.x >> 2, b = blockIdx.x & 3;
    const int d = threadIdx.x;
    const float* Ap = Alog + ((long)(br * NLAY + layer) * DINNER + d) * DSTATE;
    float Aa[16];
    bool pw = true;
    #pragma unroll
    for (int s = 0; s < 16; ++s) {
        Aa[s] = -__expf(Ap[s]);
        pw = pw && (fabsf(Aa[s] + (float)(s + 1)) < 1e-3f);
    }
    const float* recB = recbuf + ((long)(br * 4 + b) * (NCH - 1)) * 17 * 256 + d;
    float* carB = carbuf + ((long)(br * 4 + b) * NCH) * 16 * 256 + d;
    float h[16];
    #pragma unroll
    for (int s = 0; s < 16; ++s) h[s] = 0.f;
    float rh[16], rs;
    #pragma unroll
    for (int s = 0; s < 16; ++s) rh[s] = recB[s * 256];
    rs = recB[16 * 256];
    for (int c = 0; c < NCH; ++c) {
        float* car = carB + (long)c * 16 * 256;
        #pragma unroll
        for (int s = 0; s < 16; ++s) car[s * 256] = h[s];
        if (c < NCH - 1) {
            float nh[16], ns = 0.f;
            if (c + 1 < NCH - 1) {
                const float* r2 = recB + (long)(c + 1) * 17 * 256;
                #pragma unroll
                for (int s = 0; s < 16; ++s) nh[s] = r2[s * 256];
                ns = r2[16 * 256];
            } else {
                #pragma unroll
                for (int s = 0; s < 16; ++s) nh[s] = 0.f;
            }
            float P[16];
            if (pw) dA_pow(__expf(-rs), P);
            else    dA_exp(rs, Aa, P);
            #pragma unroll
            for (int s = 0; s < 16; ++s) h[s] = fmaf(h[s], P[s], rh[s]);
            #pragma unroll
            for (int s = 0; s < 16; ++s) rh[s] = nh[s];
            rs = ns;
        }
    }
}

// ---------------------------------------------------------------------------
// Scan pass 3: carry + local recurrence; yz = (y + Dp*xc)*silu(z).
// ---------------------------------------------------------------------------
__global__ __launch_bounds__(256) void scan3_k(
    const float* __restrict__ dtb, const float* __restrict__ xcb,
    const float* __restrict__ bcb, const float* __restrict__ zb,
    const float* __restrict__ Alog, const float* __restrict__ Dpar,
    const float* __restrict__ carbuf, float* __restrict__ yz, int layer)
{
    const int c = blockIdx.x, b = blockIdx.y, br = blockIdx.z;
    const int d = threadIdx.x;
    const float* car = carbuf + (((long)(br * 4 + b) * NCH + c) * 16) * 256 + d;
    float h[16];
    #pragma unroll
    for (int s = 0; s < 16; ++s) h[s] = car[s * 256];
    const float* Ap = Alog + ((long)(br * NLAY + layer) * DINNER + d) * DSTATE;
    float Aa[16];
    bool pw = true;
    #pragma unroll
    for (int s = 0; s < 16; ++s) {
        Aa[s] = -__expf(Ap[s]);
        pw = pw && (fabsf(Aa[s] + (float)(s + 1)) < 1e-3f);
    }
    const float Dp = Dpar[(br * NLAY + layer) * DINNER + d];
    const long rbase = (long)br * BT + (long)b * Tk + (long)c * LCH;
    const float* dtp = dtb + rbase * DINNER + d;
    const float* xcp = xcb + rbase * DINNER + d;
    const float* zp  = zb  + rbase * DINNER + d;
    float*       yp  = yz  + rbase * DINNER + d;
    __shared__ float bcs[LCH * 32];      // 8 KB
    {
        const float4* g = (const float4*)(bcb + rbase * 32);
        float4* l = (float4*)bcs;
        l[d] = g[d]; l[d + 256] = g[d + 256];
    }
    float dtc[UF], xcc[UF], zc[UF];
    #pragma unroll
    for (int u = 0; u < UF; ++u) {
        dtc[u] = dtp[(long)u * DINNER];
        xcc[u] = xcp[(long)u * DINNER];
        zc[u]  = zp[(long)u * DINNER];
    }
    __syncthreads();
    for (int base = 0; base < LCH; base += UF) {
        const int nb = (base + UF < LCH) ? base + UF : base;
        float dtn[UF], xcn[UF], zn[UF];
        #pragma unroll
        for (int u = 0; u < UF; ++u) {
            dtn[u] = dtp[(long)(nb + u) * DINNER];
            xcn[u] = xcp[(long)(nb + u) * DINNER];
            zn[u]  = zp[(long)(nb + u) * DINNER];
        }
        #pragma unroll
        for (int u = 0; u < UF; ++u) {
            const int t = base + u;
            const float dtv = dtc[u], xcv = xcc[u];
            const float dtxc = dtv * xcv;
            float dA[16];
            if (pw) dA_pow(__expf(-dtv), dA);
            else    dA_exp(dtv, Aa, dA);
            const float* bcT = bcs + t * 32;     // uniform addr -> broadcast
            #pragma unroll
            for (int s = 0; s < 16; ++s)
                h[s] = fmaf(dA[s], h[s], dtxc * bcT[s]);
            float y0 = 0.f, y1 = 0.f, y2 = 0.f, y3 = 0.f;
            #pragma unroll
            for (int s = 0; s < 16; s += 4) {
                y0 = fmaf(h[s+0], bcT[16+s+0], y0);
                y1 = fmaf(h[s+1], bcT[16+s+1], y1);
                y2 = fmaf(h[s+2], bcT[16+s+2], y2);
                y3 = fmaf(h[s+3], bcT[16+s+3], y3);
            }
            const float y = (y0 + y1) + (y2 + y3) + Dp * xcv;
            yp[(long)t * DINNER] = y * zc[u];
        }
        #pragma unroll
        for (int u = 0; u < UF; ++u) { dtc[u] = dtn[u]; xcc[u] = xcn[u]; zc[u] = zn[u]; }
    }
}

// ---------------------------------------------------------------------------
// mean over T then @ W_op + b_op -> z_t directly into d_out[0..1023].
// ---------------------------------------------------------------------------
__global__ __launch_bounds__(128) void meanop_k(
    const float* __restrict__ hbuf, const float* __restrict__ Wop,
    const float* __restrict__ bop, float* __restrict__ outzt)
{
    const int br = blockIdx.x >> 2, b = blockIdx.x & 3;
    const int tid = threadIdx.x;
    const float* hp = hbuf + ((long)br * BT + (long)b * Tk) * DMODEL + tid;
    float s = 0.f;
    for (int t = 0; t < Tk; ++t) s += hp[(long)t * DMODEL];
    __shared__ float hm[DMODEL];
    hm[tid] = s * (1.0f / Tk);
    __syncthreads();
    if (tid < EMBEDk) {
        float acc = bop[br * EMBEDk + tid];
        for (int k = 0; k < DMODEL; ++k)
            acc = fmaf(hm[k], Wop[(long)br * DMODEL * EMBEDk + k * EMBEDk + tid], acc);
        outzt[br * (Bk * EMBEDk) + b * EMBEDk + tid] = acc;
    }
}

// ---------------------------------------------------------------------------
// Lorentz epilogue.
// ---------------------------------------------------------------------------
__global__ __launch_bounds__(64) void final_k(
    const float* __restrict__ zt, float* __restrict__ out, const float* __restrict__ eff)
{
    const float es = tanhf(eff[0]);
    __shared__ float us[NBR][Bk][EMBEDk];
    const int t = threadIdx.x;
    if (t < 16) {
        const int br = t >> 2, b = t & 3;
        const float* z = zt + br * (Bk * EMBEDk) + b * EMBEDk;
        float n2 = 0.f;
        for (int e = 0; e < EMBEDk; ++e) { float v = z[e] * es; n2 = fmaf(v, v, n2); }
        const float n  = sqrtf(n2);
        const float nc = fminf(fmaxf(n, EPSF), MAXNF);
        const float sc = nc / fmaxf(n, EPSF);
        const float sh = sinhf(nc) / nc;
        const float fac = es * sc * sh;
        float* zh = out + 1024 + br * (Bk * (EMBEDk + 1)) + b * (EMBEDk + 1);
        float sp2 = 0.f;
        for (int e = 0; e < EMBEDk; ++e) {
            float spv = z[e] * fac;
            sp2 = fmaf(spv, spv, sp2);
            zh[1 + e] = spv;
            us[br][b][e] = spv;
        }
        const float t0 = sqrtf(1.f + sp2);
        zh[0] = t0;
        const float dd  = acoshf(fmaxf(t0, 1.f + EPSF));
        const float spn = fmaxf(sqrtf(sp2), EPSF);
        const float rr  = dd / spn;
        for (int e = 0; e < EMBEDk; ++e) us[br][b][e] *= rr;
    }
    __syncthreads();
    if (t < 4) {
        const int b = t;
        float ct[EMBEDk];
        float* cto = out + 2064 + b * EMBEDk;
        for (int e = 0; e < EMBEDk; ++e) {
            float v = us[0][b][e] + us[1][b][e] + us[2][b][e] + us[3][b][e];
            ct[e] = v; cto[e] = v;
        }
        float n2 = 0.f;
        for (int e = 0; e < EMBEDk; ++e) { float v = ct[e] * es; n2 = fmaf(v, v, n2); }
        const float n  = sqrtf(n2);
        const float nc = fminf(fmaxf(n, EPSF), MAXNF);
        const float sc = nc / fmaxf(n, EPSF);
        const float sh = sinhf(nc) / nc;
        const float fac = es * sc * sh;
        float* ch = out + 2320 + b * (EMBEDk + 1);
        float sp2 = 0.f;
        for (int e = 0; e < EMBEDk; ++e) {
            float spv = ct[e] * fac;
            sp2 = fmaf(spv, spv, sp2);
            ch[1 + e] = spv;
        }
        ch[0] = sqrtf(1.f + sp2);
    }
}

extern "C" void kernel_launch(void* const* d_in, const int* in_sizes, int n_in,
                              void* d_out, int out_size, void* d_ws, size_t ws_size,
                              hipStream_t stream)
{
    const float* X0 = (const float*)d_in[0];
    const float* X1 = (const float*)d_in[1];
    const float* X2 = (const float*)d_in[2];
    const float* X3 = (const float*)d_in[3];
    const float* W_ip   = (const float*)d_in[4];
    const float* b_ip   = (const float*)d_in[5];
    const float* W_in   = (const float*)d_in[6];
    const float* conv_w = (const float*)d_in[7];
    const float* conv_b = (const float*)d_in[8];
    const float* W_x    = (const float*)d_in[9];
    const float* W_dt   = (const float*)d_in[10];
    const float* b_dt   = (const float*)d_in[11];
    const float* A_log  = (const float*)d_in[12];
    const float* D_par  = (const float*)d_in[13];
    const float* W_out  = (const float*)d_in[14];
    const float* W_op   = (const float*)d_in[15];
    const float* b_op   = (const float*)d_in[16];
    const float* eff    = (const float*)d_in[17];
    float* out = (float*)d_out;
    float* ws  = (float*)d_ws;

    // workspace layout (floats), ~78 MB
    float* buf_h  = ws;                                  // 4*4096*128 = 2.097M
    float* buf_xp = buf_h  + (long)NBR * BT * DMODEL;    // 4*4096*256 (xp / wc panel / yz)
    float* buf_z  = buf_xp + (long)NBR * BT * DINNER;
    float* buf_xc = buf_z  + (long)NBR * BT * DINNER;
    float* buf_dt = buf_xc + (long)NBR * BT * DINNER;
    float* buf_bc = buf_dt + (long)NBR * BT * DINNER;    // 4*4096*32
    // scan records + carries alias buf_h (dead between xz-GEMM and W_out-GEMM)
    float* recbuf = buf_h;
    float* carbuf = buf_h + (long)16 * (NCH - 1) * 17 * 256;
    // dt|bc weight panel aliases buf_xp (xp dead after conv; yz written later):
    // 4 * 256 * 320 = 327,680 floats << 4.19M  ✓
    float* wcomb = buf_xp;

    // input projection, all branches in one dispatch: h0 = x @ W_ip + b_ip
    sgemm_k<2><<<dim3(BT / 64, DMODEL / 64, NBR), 256, 0, stream>>>(
        X0, X1, X2, X3, DIN, 0,
        W_ip, DMODEL, (long)DIN * DMODEL,
        buf_h, (long)BT * DMODEL, nullptr, 0, DMODEL,
        b_ip, DMODEL, DIN);

    for (int l = 0; l < NLAY; ++l) {
        // xz = h @ W_in; split -> xp, silu(z)
        sgemm_k<0><<<dim3(BT / 64, (2 * DINNER) / 64, NBR), 256, 0, stream>>>(
            buf_h, nullptr, nullptr, nullptr, DMODEL, (long)BT * DMODEL,
            W_in + (long)l * DMODEL * 2 * DINNER, 2 * DINNER,
            (long)NLAY * DMODEL * 2 * DINNER,
            buf_xp, (long)BT * DINNER, buf_z, (long)BT * DINNER, DINNER,
            nullptr, 0, DMODEL);
        // depthwise conv + silu
        conv_k<<<dim3((BT * DINNER) / 256, NBR), 256, 0, stream>>>(
            buf_xp, conv_w, conv_b, buf_xc, l);
        // build dt|bc weight panel (into buf_xp, xp now dead)
        prep_k<<<dim3(NBR, 4), 256, 0, stream>>>(W_x, W_dt, wcomb, l);
        // dt = softplus(xc @ wc[:,:256] + b_dt); bc = xc @ wc[:,256:288]
        sgemm_k<3><<<dim3(BT / 64, NWC / 64, NBR), 256, 0, stream>>>(
            buf_xc, nullptr, nullptr, nullptr, DINNER, (long)BT * DINNER,
            wcomb, NWC, (long)256 * NWC,
            buf_dt, (long)BT * DINNER, buf_bc, (long)BT * 32, DINNER,
            b_dt + l * DINNER, (long)NLAY * DINNER, DINNER);
        // chunked scan: local records -> carry scan -> local w/ carry
        scan1_k<<<dim3(NCH - 1, Bk, NBR), 256, 0, stream>>>(
            buf_dt, buf_xc, buf_bc, A_log, recbuf, l);
        scan2_k<<<16, 256, 0, stream>>>(A_log, recbuf, carbuf, l);
        scan3_k<<<dim3(NCH, Bk, NBR), 256, 0, stream>>>(
            buf_dt, buf_xc, buf_bc, buf_z, A_log, D_par, carbuf, buf_xp, l);
        // h = yz @ W_out
        sgemm_k<1><<<dim3(BT / 64, DMODEL / 64, NBR), 256, 0, stream>>>(
            buf_xp, nullptr, nullptr, nullptr, DINNER, (long)BT * DINNER,
            W_out + (long)l * DINNER * DMODEL, DMODEL,
            (long)NLAY * DINNER * DMODEL,
            buf_h, (long)BT * DMODEL, nullptr, 0, DMODEL,
            nullptr, 0, DINNER);
    }

    meanop_k<<<16, 128, 0, stream>>>(buf_h, W_op, b_op, out);
    final_k<<<1, 64, 0, stream>>>(out, out, eff);
}

// Round 8
// 509.157 us; speedup vs baseline: 1.5866x; 1.3166x over previous
//
#include <hip/hip_runtime.h>
#include <math.h>

#define NBR 4
#define NLAY 3
#define Bk 4
#define Tk 1024
#define DIN 32
#define DMODEL 128
#define DINNER 256
#define DSTATE 16
#define DTRANK 8
#define EMBEDk 64
#define BT (Bk*Tk)          /* 4096 rows per branch */
#define EPSF 1e-7f
#define MAXNF 10.0f
#define LCH 64              /* scan chunk length */
#define NCH (Tk/LCH)        /* 16 chunks */
#define UF 8                /* t-loop batch (latency amortization) */
#define NWB 320             /* dt|bc panel rows: 256 dt + 32 bc + 32 pad */

typedef __bf16 bf16x8 __attribute__((ext_vector_type(8)));
typedef float  f32x4  __attribute__((ext_vector_type(4)));
typedef unsigned short u16x8 __attribute__((ext_vector_type(8)));

__device__ __forceinline__ float siluf(float x){ return x / (1.f + __expf(-x)); }
__device__ __forceinline__ float softplusf(float x){ return (x > 20.f) ? x : log1pf(__expf(x)); }
// fp32 -> bf16 (round to nearest even)
__device__ __forceinline__ unsigned short f2b(float x){
    union { float f; unsigned u; } v; v.f = x;
    unsigned r = v.u + 0x7FFF + ((v.u >> 16) & 1);
    return (unsigned short)(r >> 16);
}

// dA[s] = q^(s+1) from q (A_s = -(s+1) fast path)
__device__ __forceinline__ void dA_pow(float q, float* dA){
    dA[0] = q;             dA[1] = q * q;
    dA[2] = dA[1] * dA[0]; dA[3] = dA[1] * dA[1];
    dA[4] = dA[3] * dA[0]; dA[5] = dA[3] * dA[1];
    dA[6] = dA[3] * dA[2]; dA[7] = dA[3] * dA[3];
    #pragma unroll
    for (int s = 8; s < 16; ++s) dA[s] = dA[s - 8] * dA[7];
}
__device__ __forceinline__ void dA_exp(float dtv, const float* Aa, float* dA){
    #pragma unroll
    for (int s = 0; s < 16; ++s) dA[s] = __expf(dtv * Aa[s]);
}

// ---------------------------------------------------------------------------
// bf16 MFMA GEMM: C = A(MxK) @ B(KxN).  A bf16 [M][K] row-major; B given
// TRANSPOSED bf16 [N][K] row-major (k contiguous -> fragment staging trivial).
// Block 64x64 tile, 4 waves each a 32x32 quadrant via 2x2x2
// mfma_f32_16x16x32_bf16, Kc=64.  LDS layout [kch][row][8bf16]: every
// fragment read is one contiguous ds_read_b128 at lane*16B.
// Verified layouts: A[m=lane&15][k=(lane>>4)*8+j]; B sym; D row=(lane>>4)*4+reg,
// col=lane&15.
// MODE 0 (xz):  n0<256 -> C0 raw (xp fp32, ld 256); n0>=256 -> C1 silu (z)
// MODE 1 (out): C0 fp32 (ld 128) + Cb bf16 dual-store
// MODE 3 (dtbc): col<256 -> C0 softplus(v+bias) (dt, ld 256);
//                col 256..287 -> C1 raw (bc, ld 32); col>=288 dropped
// ---------------------------------------------------------------------------
template<int MODE>
__global__ __launch_bounds__(256) void bgemm_k(
    const unsigned short* __restrict__ Ab, long aBr, int K,
    const unsigned short* __restrict__ Bt, long bBr,
    float* __restrict__ C0, long c0Br,
    float* __restrict__ C1, long c1Br,
    unsigned short* __restrict__ Cb, long cbBr,
    const float* __restrict__ bias, long biasBr)
{
    const int br = blockIdx.z;
    Ab += (long)br * aBr;
    Bt += (long)br * bBr;
    C0 += (long)br * c0Br;
    if (MODE == 0 || MODE == 3) C1 += (long)br * c1Br;
    if (MODE == 1) Cb += (long)br * cbBr;
    if (MODE == 3) bias += (long)br * biasBr;
    const int m0 = blockIdx.x * 64, n0 = blockIdx.y * 64;
    __shared__ __align__(16) unsigned short As[8 * 64 * 8];  // [kch][m][8]
    __shared__ __align__(16) unsigned short Bs[8 * 64 * 8];  // [kch][n][8]
    const int tid = threadIdx.x;
    const int lane = tid & 63, w = tid >> 6;
    const int wm = w >> 1, wn = w & 1;
    const int quad = lane >> 4, l15 = lane & 15;
    f32x4 acc00 = {0,0,0,0}, acc01 = {0,0,0,0}, acc10 = {0,0,0,0}, acc11 = {0,0,0,0};
    for (int kc = 0; kc < K; kc += 64) {
        #pragma unroll
        for (int it = 0; it < 2; ++it) {
            const int c = tid + it * 256;          // 0..511
            const int r = c & 63, kch = c >> 6;    // row, k-chunk(8)
            *(u16x8*)&As[(kch * 64 + r) * 8] =
                *(const u16x8*)(Ab + (long)(m0 + r) * K + kc + kch * 8);
            *(u16x8*)&Bs[(kch * 64 + r) * 8] =
                *(const u16x8*)(Bt + (long)(n0 + r) * K + kc + kch * 8);
        }
        __syncthreads();
        #pragma unroll
        for (int k0 = 0; k0 < 64; k0 += 32) {
            const int kch = (k0 >> 3) + quad;
            bf16x8 a0 = *(const bf16x8*)&As[(kch * 64 + wm * 32 +      l15) * 8];
            bf16x8 a1 = *(const bf16x8*)&As[(kch * 64 + wm * 32 + 16 + l15) * 8];
            bf16x8 b0 = *(const bf16x8*)&Bs[(kch * 64 + wn * 32 +      l15) * 8];
            bf16x8 b1 = *(const bf16x8*)&Bs[(kch * 64 + wn * 32 + 16 + l15) * 8];
            acc00 = __builtin_amdgcn_mfma_f32_16x16x32_bf16(a0, b0, acc00, 0, 0, 0);
            acc01 = __builtin_amdgcn_mfma_f32_16x16x32_bf16(a0, b1, acc01, 0, 0, 0);
            acc10 = __builtin_amdgcn_mfma_f32_16x16x32_bf16(a1, b0, acc10, 0, 0, 0);
            acc11 = __builtin_amdgcn_mfma_f32_16x16x32_bf16(a1, b1, acc11, 0, 0, 0);
        }
        __syncthreads();
    }
    #pragma unroll
    for (int e = 0; e < 4; ++e) {
        f32x4 a = (e == 0) ? acc00 : (e == 1) ? acc01 : (e == 2) ? acc10 : acc11;
        const int msub = (e >> 1) * 16, nsub = (e & 1) * 16;
        const int col = n0 + wn * 32 + nsub + l15;
        #pragma unroll
        for (int r = 0; r < 4; ++r) {
            const int row = m0 + wm * 32 + msub + quad * 4 + r;
            const float v = a[r];
            if (MODE == 0) {
                if (n0 < 256) C0[(long)row * 256 + col] = v;
                else          C1[(long)row * 256 + (col - 256)] = siluf(v);
            } else if (MODE == 1) {
                C0[(long)row * 128 + col] = v;
                Cb[(long)row * 128 + col] = f2b(v);
            } else {
                if (col < 256)      C0[(long)row * 256 + col] = softplusf(v + bias[col]);
                else if (col < 288) C1[(long)row * 32 + (col - 256)] = v;
            }
        }
    }
}

// ---------------------------------------------------------------------------
// Transpose + cvt: o_bf16[n][k] = W_f32[k][n].  64x64 tiles via LDS.
// ---------------------------------------------------------------------------
__global__ __launch_bounds__(256) void prepT_k(
    const float* __restrict__ W, unsigned short* __restrict__ o,
    int Kd, int Nd, long wBr, long oBr)
{
    const int br = blockIdx.z;
    W += (long)br * wBr; o += (long)br * oBr;
    const int n0 = blockIdx.x * 64, k0 = blockIdx.y * 64;
    __shared__ float tile[64][65];
    const int t = threadIdx.x;
    #pragma unroll
    for (int i = 0; i < 16; ++i) {
        int idx = t + i * 256;
        int kl = idx >> 6, nl = idx & 63;
        tile[kl][nl] = W[(long)(k0 + kl) * Nd + n0 + nl];
    }
    __syncthreads();
    #pragma unroll
    for (int i = 0; i < 16; ++i) {
        int idx = t + i * 256;
        int nl = idx >> 6, kl = idx & 63;
        o[(long)(n0 + nl) * Kd + k0 + kl] = f2b(tile[kl][nl]);
    }
}

// ---------------------------------------------------------------------------
// Build wcombT bf16 [320 n][256 k]:
//  n<256:   wcombT[n][k] = sum_r Wx[k][r]*Wdt[r][n]  (dt = softplus(xc@.. + b))
//  256..287: Wx[k][8+(n-256)]  (B,C);  288..319: 0
// ---------------------------------------------------------------------------
__global__ __launch_bounds__(256) void prepC_k(
    const float* __restrict__ Wx, const float* __restrict__ Wdt,
    unsigned short* __restrict__ o, int layer)
{
    const int n = blockIdx.x, br = blockIdx.y;
    const int k = threadIdx.x;
    const float* WxP = Wx + (long)(br * NLAY + layer) * DINNER * 40;
    float v;
    if (n < 256) {
        const float* WdtP = Wdt + (long)(br * NLAY + layer) * DTRANK * DINNER;
        float s = 0.f;
        #pragma unroll
        for (int r = 0; r < 8; ++r) s = fmaf(WxP[k * 40 + r], WdtP[r * DINNER + n], s);
        v = s;
    } else if (n < 288) {
        v = WxP[k * 40 + 8 + (n - 256)];
    } else {
        v = 0.f;
    }
    o[(long)br * NWB * DINNER + (long)n * DINNER + k] = f2b(v);
}

// ---------------------------------------------------------------------------
// fp32 input projection (K=32): h = x @ W_ip + b_ip, + bf16 dual-store.
// 64x64 tile, 4x4/thread, conflict-free stride-4 (round 1-4 kernel).
// ---------------------------------------------------------------------------
__global__ __launch_bounds__(256) void proj_k(
    const float* __restrict__ A0, const float* __restrict__ A1,
    const float* __restrict__ A2, const float* __restrict__ A3,
    const float* __restrict__ Bw, const float* __restrict__ bias,
    float* __restrict__ C, unsigned short* __restrict__ Cb)
{
    const int br = blockIdx.z;
    const float* A = (br == 1) ? A1 : (br == 2) ? A2 : (br == 3) ? A3 : A0;
    Bw   += (long)br * DIN * DMODEL;
    bias += (long)br * DMODEL;
    C    += (long)br * BT * DMODEL;
    Cb   += (long)br * BT * DMODEL;
    const int m0 = blockIdx.x * 64, n0 = blockIdx.y * 64;
    __shared__ float As[32][68];
    __shared__ float Bs[32][68];
    const int tid = threadIdx.x;
    const int tx = tid & 15, ty = tid >> 4;
    float acc[4][4] = {};
    {
        #pragma unroll
        for (int it = 0; it < 2; ++it) {
            int id = tid + it * 256;
            int r = id >> 3, c4 = (id & 7) << 2;
            float4 v = *(const float4*)(A + (long)(m0 + r) * DIN + c4);
            As[c4+0][r] = v.x; As[c4+1][r] = v.y; As[c4+2][r] = v.z; As[c4+3][r] = v.w;
            int rb = id >> 4, cb = (id & 15) << 2;
            *(float4*)&Bs[rb][cb] = *(const float4*)(Bw + (long)rb * DMODEL + n0 + cb);
        }
        __syncthreads();
        #pragma unroll
        for (int kk = 0; kk < 32; ++kk) {
            float4 a4 = *(const float4*)&As[kk][ty << 2];
            float4 b4 = *(const float4*)&Bs[kk][tx << 2];
            float av[4] = {a4.x, a4.y, a4.z, a4.w};
            float bv[4] = {b4.x, b4.y, b4.z, b4.w};
            #pragma unroll
            for (int i = 0; i < 4; ++i)
                #pragma unroll
                for (int j = 0; j < 4; ++j)
                    acc[i][j] = fmaf(av[i], bv[j], acc[i][j]);
        }
    }
    const int col = n0 + (tx << 2);
    float bs[4];
    #pragma unroll
    for (int j = 0; j < 4; ++j) bs[j] = bias[col + j];
    #pragma unroll
    for (int i = 0; i < 4; ++i) {
        const int row = m0 + (ty << 2) + i;
        #pragma unroll
        for (int j = 0; j < 4; ++j) {
            float v = acc[i][j] + bs[j];
            C[(long)row * DMODEL + col + j]  = v;
            Cb[(long)row * DMODEL + col + j] = f2b(v);
        }
    }
}

// ---------------------------------------------------------------------------
// Depthwise causal conv (4 taps) + bias + silu -> xc fp32 + xc bf16.
// ---------------------------------------------------------------------------
__global__ __launch_bounds__(256) void conv_k(
    const float* __restrict__ xp, const float* __restrict__ cw,
    const float* __restrict__ cb, float* __restrict__ xc,
    unsigned short* __restrict__ xcb, int layer)
{
    const int br = blockIdx.y;
    const long base = (long)br * BT * DINNER;
    const int idx = blockIdx.x * 256 + threadIdx.x;
    const int d = idx & (DINNER - 1);
    const int row = idx >> 8;
    const int t = row & (Tk - 1);
    const float4 w4 = *(const float4*)(cw + ((long)(br * NLAY + layer) * DINNER + d) * 4);
    const float wv[4] = {w4.x, w4.y, w4.z, w4.w};
    float acc = cb[(br * NLAY + layer) * DINNER + d];
    const float* xpb = xp + base + idx;
    #pragma unroll
    for (int k = 0; k < 4; ++k) {
        int tt = t + k - 3;
        if (tt >= 0) acc = fmaf(xpb[(long)(k - 3) * DINNER], wv[k], acc);
    }
    const float v = siluf(acc);
    xc[base + idx]  = v;
    xcb[base + idx] = f2b(v);
}

// ---------------------------------------------------------------------------
// Scan pass 1: per-chunk local recurrence from h=0 -> record (h_end[16], sumdt).
// ---------------------------------------------------------------------------
__global__ __launch_bounds__(256) void scan1_k(
    const float* __restrict__ dtb, const float* __restrict__ xcb,
    const float* __restrict__ bcb, const float* __restrict__ Alog,
    float* __restrict__ recbuf, int layer)
{
    const int c = blockIdx.x, b = blockIdx.y, br = blockIdx.z;
    const int d = threadIdx.x;
    const float* Ap = Alog + ((long)(br * NLAY + layer) * DINNER + d) * DSTATE;
    float Aa[16];
    bool pw = true;
    #pragma unroll
    for (int s = 0; s < 16; ++s) {
        Aa[s] = -__expf(Ap[s]);
        pw = pw && (fabsf(Aa[s] + (float)(s + 1)) < 1e-3f);
    }
    const long rbase = (long)br * BT + (long)b * Tk + (long)c * LCH;
    const float* dtp = dtb + rbase * DINNER + d;
    const float* xcp = xcb + rbase * DINNER + d;
    __shared__ float bcs[LCH * 32];
    {
        const float4* g = (const float4*)(bcb + rbase * 32);
        float4* l = (float4*)bcs;
        l[d] = g[d]; l[d + 256] = g[d + 256];
    }
    float dtc[UF], xcc[UF];
    #pragma unroll
    for (int u = 0; u < UF; ++u) {
        dtc[u] = dtp[(long)u * DINNER];
        xcc[u] = xcp[(long)u * DINNER];
    }
    __syncthreads();
    float h[16];
    #pragma unroll
    for (int s = 0; s < 16; ++s) h[s] = 0.f;
    float sumdt = 0.f;
    for (int base = 0; base < LCH; base += UF) {
        const int nb = (base + UF < LCH) ? base + UF : base;
        float dtn[UF], xcn[UF];
        #pragma unroll
        for (int u = 0; u < UF; ++u) {
            dtn[u] = dtp[(long)(nb + u) * DINNER];
            xcn[u] = xcp[(long)(nb + u) * DINNER];
        }
        #pragma unroll
        for (int u = 0; u < UF; ++u) {
            const int t = base + u;
            const float dtv = dtc[u];
            const float dtxc = dtv * xcc[u];
            sumdt += dtv;
            float dA[16];
            if (pw) dA_pow(__expf(-dtv), dA);
            else    dA_exp(dtv, Aa, dA);
            const float* bcT = bcs + t * 32;
            #pragma unroll
            for (int s = 0; s < 16; ++s)
                h[s] = fmaf(dA[s], h[s], dtxc * bcT[s]);
        }
        #pragma unroll
        for (int u = 0; u < UF; ++u) { dtc[u] = dtn[u]; xcc[u] = xcn[u]; }
    }
    float* sb = recbuf + (((long)(br * 4 + b) * (NCH - 1) + c) * 17) * 256 + d;
    #pragma unroll
    for (int s = 0; s < 16; ++s) sb[s * 256] = h[s];
    sb[16 * 256] = sumdt;
}

// ---------------------------------------------------------------------------
// Scan pass 2: sequential fold over chunk records -> chunk-start carries.
// ---------------------------------------------------------------------------
__global__ __launch_bounds__(256) void scan2_k(
    const float* __restrict__ Alog, const float* __restrict__ recbuf,
    float* __restrict__ carbuf, int layer)
{
    const int br = blockIdx.x >> 2, b = blockIdx.x & 3;
    const int d = threadIdx.x;
    const float* Ap = Alog + ((long)(br * NLAY + layer) * DINNER + d) * DSTATE;
    float Aa[16];
    bool pw = true;
    #pragma unroll
    for (int s = 0; s < 16; ++s) {
        Aa[s] = -__expf(Ap[s]);
        pw = pw && (fabsf(Aa[s] + (float)(s + 1)) < 1e-3f);
    }
    const float* recB = recbuf + ((long)(br * 4 + b) * (NCH - 1)) * 17 * 256 + d;
    float* carB = carbuf + ((long)(br * 4 + b) * NCH) * 16 * 256 + d;
    float h[16];
    #pragma unroll
    for (int s = 0; s < 16; ++s) h[s] = 0.f;
    float rh[16], rs;
    #pragma unroll
    for (int s = 0; s < 16; ++s) rh[s] = recB[s * 256];
    rs = recB[16 * 256];
    for (int c = 0; c < NCH; ++c) {
        float* car = carB + (long)c * 16 * 256;
        #pragma unroll
        for (int s = 0; s < 16; ++s) car[s * 256] = h[s];
        if (c < NCH - 1) {
            float nh[16], ns = 0.f;
            if (c + 1 < NCH - 1) {
                const float* r2 = recB + (long)(c + 1) * 17 * 256;
                #pragma unroll
                for (int s = 0; s < 16; ++s) nh[s] = r2[s * 256];
                ns = r2[16 * 256];
            } else {
                #pragma unroll
                for (int s = 0; s < 16; ++s) nh[s] = 0.f;
            }
            float P[16];
            if (pw) dA_pow(__expf(-rs), P);
            else    dA_exp(rs, Aa, P);
            #pragma unroll
            for (int s = 0; s < 16; ++s) h[s] = fmaf(h[s], P[s], rh[s]);
            #pragma unroll
            for (int s = 0; s < 16; ++s) rh[s] = nh[s];
            rs = ns;
        }
    }
}

// ---------------------------------------------------------------------------
// Scan pass 3: carry + local recurrence; yz = (y + Dp*xc)*silu(z) -> bf16.
// ---------------------------------------------------------------------------
__global__ __launch_bounds__(256) void scan3_k(
    const float* __restrict__ dtb, const float* __restrict__ xcb,
    const float* __restrict__ bcb, const float* __restrict__ zb,
    const float* __restrict__ Alog, const float* __restrict__ Dpar,
    const float* __restrict__ carbuf, unsigned short* __restrict__ yzb, int layer)
{
    const int c = blockIdx.x, b = blockIdx.y, br = blockIdx.z;
    const int d = threadIdx.x;
    const float* car = carbuf + (((long)(br * 4 + b) * NCH + c) * 16) * 256 + d;
    float h[16];
    #pragma unroll
    for (int s = 0; s < 16; ++s) h[s] = car[s * 256];
    const float* Ap = Alog + ((long)(br * NLAY + layer) * DINNER + d) * DSTATE;
    float Aa[16];
    bool pw = true;
    #pragma unroll
    for (int s = 0; s < 16; ++s) {
        Aa[s] = -__expf(Ap[s]);
        pw = pw && (fabsf(Aa[s] + (float)(s + 1)) < 1e-3f);
    }
    const float Dp = Dpar[(br * NLAY + layer) * DINNER + d];
    const long rbase = (long)br * BT + (long)b * Tk + (long)c * LCH;
    const float* dtp = dtb + rbase * DINNER + d;
    const float* xcp = xcb + rbase * DINNER + d;
    const float* zp  = zb  + rbase * DINNER + d;
    unsigned short* yp = yzb + rbase * DINNER + d;
    __shared__ float bcs[LCH * 32];
    {
        const float4* g = (const float4*)(bcb + rbase * 32);
        float4* l = (float4*)bcs;
        l[d] = g[d]; l[d + 256] = g[d + 256];
    }
    float dtc[UF], xcc[UF], zc[UF];
    #pragma unroll
    for (int u = 0; u < UF; ++u) {
        dtc[u] = dtp[(long)u * DINNER];
        xcc[u] = xcp[(long)u * DINNER];
        zc[u]  = zp[(long)u * DINNER];
    }
    __syncthreads();
    for (int base = 0; base < LCH; base += UF) {
        const int nb = (base + UF < LCH) ? base + UF : base;
        float dtn[UF], xcn[UF], zn[UF];
        #pragma unroll
        for (int u = 0; u < UF; ++u) {
            dtn[u] = dtp[(long)(nb + u) * DINNER];
            xcn[u] = xcp[(long)(nb + u) * DINNER];
            zn[u]  = zp[(long)(nb + u) * DINNER];
        }
        #pragma unroll
        for (int u = 0; u < UF; ++u) {
            const int t = base + u;
            const float dtv = dtc[u], xcv = xcc[u];
            const float dtxc = dtv * xcv;
            float dA[16];
            if (pw) dA_pow(__expf(-dtv), dA);
            else    dA_exp(dtv, Aa, dA);
            const float* bcT = bcs + t * 32;
            #pragma unroll
            for (int s = 0; s < 16; ++s)
                h[s] = fmaf(dA[s], h[s], dtxc * bcT[s]);
            float y0 = 0.f, y1 = 0.f, y2 = 0.f, y3 = 0.f;
            #pragma unroll
            for (int s = 0; s < 16; s += 4) {
                y0 = fmaf(h[s+0], bcT[16+s+0], y0);
                y1 = fmaf(h[s+1], bcT[16+s+1], y1);
                y2 = fmaf(h[s+2], bcT[16+s+2], y2);
                y3 = fmaf(h[s+3], bcT[16+s+3], y3);
            }
            const float y = (y0 + y1) + (y2 + y3) + Dp * xcv;
            yp[(long)t * DINNER] = f2b(y * zc[u]);
        }
        #pragma unroll
        for (int u = 0; u < UF; ++u) { dtc[u] = dtn[u]; xcc[u] = xcn[u]; zc[u] = zn[u]; }
    }
}

// ---------------------------------------------------------------------------
// mean over T then @ W_op + b_op -> z_t directly into d_out[0..1023].
// ---------------------------------------------------------------------------
__global__ __launch_bounds__(128) void meanop_k(
    const float* __restrict__ hbuf, const float* __restrict__ Wop,
    const float* __restrict__ bop, float* __restrict__ outzt)
{
    const int br = blockIdx.x >> 2, b = blockIdx.x & 3;
    const int tid = threadIdx.x;
    const float* hp = hbuf + ((long)br * BT + (long)b * Tk) * DMODEL + tid;
    float s = 0.f;
    for (int t = 0; t < Tk; ++t) s += hp[(long)t * DMODEL];
    __shared__ float hm[DMODEL];
    hm[tid] = s * (1.0f / Tk);
    __syncthreads();
    if (tid < EMBEDk) {
        float acc = bop[br * EMBEDk + tid];
        for (int k = 0; k < DMODEL; ++k)
            acc = fmaf(hm[k], Wop[(long)br * DMODEL * EMBEDk + k * EMBEDk + tid], acc);
        outzt[br * (Bk * EMBEDk) + b * EMBEDk + tid] = acc;
    }
}

// ---------------------------------------------------------------------------
// Lorentz epilogue.
// ---------------------------------------------------------------------------
__global__ __launch_bounds__(64) void final_k(
    const float* __restrict__ zt, float* __restrict__ out, const float* __restrict__ eff)
{
    const float es = tanhf(eff[0]);
    __shared__ float us[NBR][Bk][EMBEDk];
    const int t = threadIdx.x;
    if (t < 16) {
        const int br = t >> 2, b = t & 3;
        const float* z = zt + br * (Bk * EMBEDk) + b * EMBEDk;
        float n2 = 0.f;
        for (int e = 0; e < EMBEDk; ++e) { float v = z[e] * es; n2 = fmaf(v, v, n2); }
        const float n  = sqrtf(n2);
        const float nc = fminf(fmaxf(n, EPSF), MAXNF);
        const float sc = nc / fmaxf(n, EPSF);
        const float sh = sinhf(nc) / nc;
        const float fac = es * sc * sh;
        float* zh = out + 1024 + br * (Bk * (EMBEDk + 1)) + b * (EMBEDk + 1);
        float sp2 = 0.f;
        for (int e = 0; e < EMBEDk; ++e) {
            float spv = z[e] * fac;
            sp2 = fmaf(spv, spv, sp2);
            zh[1 + e] = spv;
            us[br][b][e] = spv;
        }
        const float t0 = sqrtf(1.f + sp2);
        zh[0] = t0;
        const float dd  = acoshf(fmaxf(t0, 1.f + EPSF));
        const float spn = fmaxf(sqrtf(sp2), EPSF);
        const float rr  = dd / spn;
        for (int e = 0; e < EMBEDk; ++e) us[br][b][e] *= rr;
    }
    __syncthreads();
    if (t < 4) {
        const int b = t;
        float ct[EMBEDk];
        float* cto = out + 2064 + b * EMBEDk;
        for (int e = 0; e < EMBEDk; ++e) {
            float v = us[0][b][e] + us[1][b][e] + us[2][b][e] + us[3][b][e];
            ct[e] = v; cto[e] = v;
        }
        float n2 = 0.f;
        for (int e = 0; e < EMBEDk; ++e) { float v = ct[e] * es; n2 = fmaf(v, v, n2); }
        const float n  = sqrtf(n2);
        const float nc = fminf(fmaxf(n, EPSF), MAXNF);
        const float sc = nc / fmaxf(n, EPSF);
        const float sh = sinhf(nc) / nc;
        const float fac = es * sc * sh;
        float* ch = out + 2320 + b * (EMBEDk + 1);
        float sp2 = 0.f;
        for (int e = 0; e < EMBEDk; ++e) {
            float spv = ct[e] * fac;
            sp2 = fmaf(spv, spv, sp2);
            ch[1 + e] = spv;
        }
        ch[0] = sqrtf(1.f + sp2);
    }
}

extern "C" void kernel_launch(void* const* d_in, const int* in_sizes, int n_in,
                              void* d_out, int out_size, void* d_ws, size_t ws_size,
                              hipStream_t stream)
{
    const float* X0 = (const float*)d_in[0];
    const float* X1 = (const float*)d_in[1];
    const float* X2 = (const float*)d_in[2];
    const float* X3 = (const float*)d_in[3];
    const float* W_ip   = (const float*)d_in[4];
    const float* b_ip   = (const float*)d_in[5];
    const float* W_in   = (const float*)d_in[6];
    const float* conv_w = (const float*)d_in[7];
    const float* conv_b = (const float*)d_in[8];
    const float* W_x    = (const float*)d_in[9];
    const float* W_dt   = (const float*)d_in[10];
    const float* b_dt   = (const float*)d_in[11];
    const float* A_log  = (const float*)d_in[12];
    const float* D_par  = (const float*)d_in[13];
    const float* W_out  = (const float*)d_in[14];
    const float* W_op   = (const float*)d_in[15];
    const float* b_op   = (const float*)d_in[16];
    const float* eff    = (const float*)d_in[17];
    float* out = (float*)d_out;
    float* ws  = (float*)d_ws;

    // workspace layout (floats), ~92 MB
    float* buf_h  = ws;                                  // 2.097M (+ rec/car alias)
    float* buf_xp = buf_h  + (long)NBR * BT * DMODEL;    // 4.19M fp32 xp (yz_bf aliases front half)
    float* buf_z  = buf_xp + (long)NBR * BT * DINNER;
    float* buf_xc = buf_z  + (long)NBR * BT * DINNER;
    float* buf_dt = buf_xc + (long)NBR * BT * DINNER;
    float* buf_bc = buf_dt + (long)NBR * BT * DINNER;    // 0.524M
    unsigned short* h_bf  = (unsigned short*)(buf_bc + (long)NBR * BT * 32);  // 2.097M u16
    unsigned short* xc_bf = h_bf + (long)NBR * BT * DMODEL;                   // 4.19M u16
    unsigned short* WinT  = xc_bf + (long)NBR * BT * DINNER;                  // 4*512*128 u16
    unsigned short* WcT   = WinT + (long)NBR * 512 * DMODEL;                  // 4*320*256 u16
    unsigned short* WoT   = WcT  + (long)NBR * NWB * DINNER;                  // 4*128*256 u16
    // scan records + carries alias buf_h (h fp32 only read by meanop at end;
    // bgemm_k<1> rewrites all of buf_h each layer after the scans)
    float* recbuf = buf_h;
    float* carbuf = buf_h + (long)16 * (NCH - 1) * 17 * 256;
    // yz bf16 aliases buf_xp front (xp fp32 dead after conv; rewritten next layer)
    unsigned short* yz_bf = (unsigned short*)buf_xp;

    // input projection (fp32, K=32): h = x @ W_ip + b_ip  (+ bf16 dual store)
    proj_k<<<dim3(BT / 64, DMODEL / 64, NBR), 256, 0, stream>>>(
        X0, X1, X2, X3, W_ip, b_ip, buf_h, h_bf);

    for (int l = 0; l < NLAY; ++l) {
        // W_in^T -> bf16 [512][128]
        prepT_k<<<dim3(512 / 64, DMODEL / 64, NBR), 256, 0, stream>>>(
            W_in + (long)l * DMODEL * 512, WinT, DMODEL, 512,
            (long)NLAY * DMODEL * 512, (long)512 * DMODEL);
        // xz = h @ W_in (bf16 MFMA); split -> xp fp32, silu(z) fp32
        bgemm_k<0><<<dim3(BT / 64, 512 / 64, NBR), 256, 0, stream>>>(
            h_bf, (long)BT * DMODEL, DMODEL,
            WinT, (long)512 * DMODEL,
            buf_xp, (long)BT * DINNER, buf_z, (long)BT * DINNER,
            nullptr, 0, nullptr, 0);
        // depthwise conv + silu -> xc fp32 + bf16
        conv_k<<<dim3((BT * DINNER) / 256, NBR), 256, 0, stream>>>(
            buf_xp, conv_w, conv_b, buf_xc, xc_bf, l);
        // weight panels: wcombT (dt|bc fused) and W_out^T
        prepC_k<<<dim3(NWB, NBR), 256, 0, stream>>>(W_x, W_dt, WcT, l);
        prepT_k<<<dim3(DMODEL / 64, DINNER / 64, NBR), 256, 0, stream>>>(
            W_out + (long)l * DINNER * DMODEL, WoT, DINNER, DMODEL,
            (long)NLAY * DINNER * DMODEL, (long)DMODEL * DINNER);
        // dt = softplus(xc @ wc + b_dt); bc = xc @ wcBC   (bf16 MFMA)
        bgemm_k<3><<<dim3(BT / 64, NWB / 64, NBR), 256, 0, stream>>>(
            xc_bf, (long)BT * DINNER, DINNER,
            WcT, (long)NWB * DINNER,
            buf_dt, (long)BT * DINNER, buf_bc, (long)BT * 32,
            nullptr, 0, b_dt + l * DINNER, (long)NLAY * DINNER);
        // chunked scan: local records -> carry scan -> local w/ carry -> yz bf16
        scan1_k<<<dim3(NCH - 1, Bk, NBR), 256, 0, stream>>>(
            buf_dt, buf_xc, buf_bc, A_log, recbuf, l);
        scan2_k<<<16, 256, 0, stream>>>(A_log, recbuf, carbuf, l);
        scan3_k<<<dim3(NCH, Bk, NBR), 256, 0, stream>>>(
            buf_dt, buf_xc, buf_bc, buf_z, A_log, D_par, carbuf, yz_bf, l);
        // h = yz @ W_out (bf16 MFMA) -> h fp32 + h bf16
        bgemm_k<1><<<dim3(BT / 64, DMODEL / 64, NBR), 256, 0, stream>>>(
            yz_bf, (long)BT * DINNER, DINNER,
            WoT, (long)DMODEL * DINNER,
            buf_h, (long)BT * DMODEL, nullptr, 0,
            h_bf, (long)BT * DMODEL, nullptr, 0);
    }

    meanop_k<<<16, 128, 0, stream>>>(buf_h, W_op, b_op, out);
    final_k<<<1, 64, 0, stream>>>(out, out, eff);
}

// Round 9
// 471.758 us; speedup vs baseline: 1.7123x; 1.0793x over previous
//
#include <hip/hip_runtime.h>
#include <math.h>

#define NBR 4
#define NLAY 3
#define Bk 4
#define Tk 1024
#define DIN 32
#define DMODEL 128
#define DINNER 256
#define DSTATE 16
#define DTRANK 8
#define EMBEDk 64
#define BT (Bk*Tk)          /* 4096 rows per branch */
#define EPSF 1e-7f
#define MAXNF 10.0f
#define LCH 64              /* scan chunk length */
#define NCH (Tk/LCH)        /* 16 chunks */
#define UF 8                /* t-loop batch (latency amortization) */
#define NWB 320             /* dt|bc panel rows: 256 dt + 32 bc + 32 pad */

typedef __bf16 bf16x8 __attribute__((ext_vector_type(8)));
typedef float  f32x4  __attribute__((ext_vector_type(4)));
typedef unsigned short u16x8 __attribute__((ext_vector_type(8)));

__device__ __forceinline__ float siluf(float x){ return x / (1.f + __expf(-x)); }
__device__ __forceinline__ float softplusf(float x){ return (x > 20.f) ? x : log1pf(__expf(x)); }
__device__ __forceinline__ unsigned short f2b(float x){
    union { float f; unsigned u; } v; v.f = x;
    unsigned r = v.u + 0x7FFF + ((v.u >> 16) & 1);
    return (unsigned short)(r >> 16);
}
__device__ __forceinline__ float b2f(unsigned short u){
    union { unsigned u; float f; } v; v.u = ((unsigned)u) << 16; return v.f;
}

// dA[s] = q^(s+1) from q (A_s = -(s+1) fast path)
__device__ __forceinline__ void dA_pow(float q, float* dA){
    dA[0] = q;             dA[1] = q * q;
    dA[2] = dA[1] * dA[0]; dA[3] = dA[1] * dA[1];
    dA[4] = dA[3] * dA[0]; dA[5] = dA[3] * dA[1];
    dA[6] = dA[3] * dA[2]; dA[7] = dA[3] * dA[3];
    #pragma unroll
    for (int s = 8; s < 16; ++s) dA[s] = dA[s - 8] * dA[7];
}
__device__ __forceinline__ void dA_exp(float dtv, const float* Aa, float* dA){
    #pragma unroll
    for (int s = 0; s < 16; ++s) dA[s] = __expf(dtv * Aa[s]);
}

// ---------------------------------------------------------------------------
// bf16 MFMA GEMM: C = A(MxK) @ B(KxN).  A bf16 [M][K]; B TRANSPOSED bf16
// [N][K] (k contiguous).  64x64 tile, 4 waves (32x32 quadrants, 2x2x2
// mfma_f32_16x16x32_bf16), Kc=64.  LDS [kch][row][8]: fragment = 1
// ds_read_b128 at lane*16B.
// MODE 0 (xz):  col<256 -> Cb bf16 (xp); col>=256 -> C1 fp32 silu (z)
// MODE 1 (out): C0 fp32 (ld 128)
// MODE 3 (dtbc): col<256 -> C0 softplus(v+bias) (dt fp32 ld 256);
//                col 256..287 -> C1 fp32 (bc ld 32); col>=288 dropped
// ---------------------------------------------------------------------------
template<int MODE>
__global__ __launch_bounds__(256) void bgemm_k(
    const unsigned short* __restrict__ Ab, long aBr, int K,
    const unsigned short* __restrict__ Bt, long bBr,
    float* __restrict__ C0, long c0Br,
    float* __restrict__ C1, long c1Br,
    unsigned short* __restrict__ Cb, long cbBr,
    const float* __restrict__ bias, long biasBr)
{
    const int br = blockIdx.z;
    Ab += (long)br * aBr;
    Bt += (long)br * bBr;
    if (MODE == 1 || MODE == 3) C0 += (long)br * c0Br;
    if (MODE == 0 || MODE == 3) C1 += (long)br * c1Br;
    if (MODE == 0) Cb += (long)br * cbBr;
    if (MODE == 3) bias += (long)br * biasBr;
    const int m0 = blockIdx.x * 64, n0 = blockIdx.y * 64;
    __shared__ __align__(16) unsigned short As[8 * 64 * 8];  // [kch][m][8]
    __shared__ __align__(16) unsigned short Bs[8 * 64 * 8];  // [kch][n][8]
    const int tid = threadIdx.x;
    const int lane = tid & 63, w = tid >> 6;
    const int wm = w >> 1, wn = w & 1;
    const int quad = lane >> 4, l15 = lane & 15;
    f32x4 acc00 = {0,0,0,0}, acc01 = {0,0,0,0}, acc10 = {0,0,0,0}, acc11 = {0,0,0,0};
    for (int kc = 0; kc < K; kc += 64) {
        #pragma unroll
        for (int it = 0; it < 2; ++it) {
            const int c = tid + it * 256;
            const int r = c & 63, kch = c >> 6;
            *(u16x8*)&As[(kch * 64 + r) * 8] =
                *(const u16x8*)(Ab + (long)(m0 + r) * K + kc + kch * 8);
            *(u16x8*)&Bs[(kch * 64 + r) * 8] =
                *(const u16x8*)(Bt + (long)(n0 + r) * K + kc + kch * 8);
        }
        __syncthreads();
        #pragma unroll
        for (int k0 = 0; k0 < 64; k0 += 32) {
            const int kch = (k0 >> 3) + quad;
            bf16x8 a0 = *(const bf16x8*)&As[(kch * 64 + wm * 32 +      l15) * 8];
            bf16x8 a1 = *(const bf16x8*)&As[(kch * 64 + wm * 32 + 16 + l15) * 8];
            bf16x8 b0 = *(const bf16x8*)&Bs[(kch * 64 + wn * 32 +      l15) * 8];
            bf16x8 b1 = *(const bf16x8*)&Bs[(kch * 64 + wn * 32 + 16 + l15) * 8];
            acc00 = __builtin_amdgcn_mfma_f32_16x16x32_bf16(a0, b0, acc00, 0, 0, 0);
            acc01 = __builtin_amdgcn_mfma_f32_16x16x32_bf16(a0, b1, acc01, 0, 0, 0);
            acc10 = __builtin_amdgcn_mfma_f32_16x16x32_bf16(a1, b0, acc10, 0, 0, 0);
            acc11 = __builtin_amdgcn_mfma_f32_16x16x32_bf16(a1, b1, acc11, 0, 0, 0);
        }
        __syncthreads();
    }
    #pragma unroll
    for (int e = 0; e < 4; ++e) {
        f32x4 a = (e == 0) ? acc00 : (e == 1) ? acc01 : (e == 2) ? acc10 : acc11;
        const int msub = (e >> 1) * 16, nsub = (e & 1) * 16;
        const int col = n0 + wn * 32 + nsub + l15;
        #pragma unroll
        for (int r = 0; r < 4; ++r) {
            const int row = m0 + wm * 32 + msub + quad * 4 + r;
            const float v = a[r];
            if (MODE == 0) {
                if (n0 < 256) Cb[(long)row * 256 + col] = f2b(v);
                else          C1[(long)row * 256 + (col - 256)] = siluf(v);
            } else if (MODE == 1) {
                C0[(long)row * 128 + col] = v;
            } else {
                if (col < 256)      C0[(long)row * 256 + col] = softplusf(v + bias[col]);
                else if (col < 288) C1[(long)row * 32 + (col - 256)] = v;
            }
        }
    }
}

// ---------------------------------------------------------------------------
// Transpose + cvt: o_bf16[n][k] = W_f32[k][n].  64x64 tiles via LDS.
// ---------------------------------------------------------------------------
__global__ __launch_bounds__(256) void prepT_k(
    const float* __restrict__ W, unsigned short* __restrict__ o,
    int Kd, int Nd, long wBr, long oBr)
{
    const int br = blockIdx.z;
    W += (long)br * wBr; o += (long)br * oBr;
    const int n0 = blockIdx.x * 64, k0 = blockIdx.y * 64;
    __shared__ float tile[64][65];
    const int t = threadIdx.x;
    #pragma unroll
    for (int i = 0; i < 16; ++i) {
        int idx = t + i * 256;
        int kl = idx >> 6, nl = idx & 63;
        tile[kl][nl] = W[(long)(k0 + kl) * Nd + n0 + nl];
    }
    __syncthreads();
    #pragma unroll
    for (int i = 0; i < 16; ++i) {
        int idx = t + i * 256;
        int nl = idx >> 6, kl = idx & 63;
        o[(long)(n0 + nl) * Kd + k0 + kl] = f2b(tile[kl][nl]);
    }
}

// ---------------------------------------------------------------------------
// fp32 weight-product GEMM (once, at start): Wtmp[p][br] = Wout_p @ Win_{p+1}
// M=256, K=128, N=512; z = p*4+br.  64x64 tile, 4x4/thread (round-7 kernel).
// ---------------------------------------------------------------------------
__global__ __launch_bounds__(256) void sgemmW_k(
    const float* __restrict__ Wout, const float* __restrict__ Win,
    float* __restrict__ Wtmp)
{
    const int z = blockIdx.z, p = z >> 2, br = z & 3;
    const float* A  = Wout + (long)(br * NLAY + p) * DINNER * DMODEL;       // [256][128]
    const float* Bw = Win  + (long)(br * NLAY + p + 1) * DMODEL * 512;      // [128][512]
    float* C = Wtmp + (long)z * DINNER * 512;                               // [256][512]
    const int m0 = blockIdx.x * 64, n0 = blockIdx.y * 64;
    __shared__ float As[32][68];
    __shared__ float Bs[32][68];
    const int tid = threadIdx.x;
    const int tx = tid & 15, ty = tid >> 4;
    float acc[4][4] = {};
    for (int kc = 0; kc < DMODEL; kc += 32) {
        #pragma unroll
        for (int it = 0; it < 2; ++it) {
            int id = tid + it * 256;
            int r = id >> 3, c4 = (id & 7) << 2;
            float4 v = *(const float4*)(A + (long)(m0 + r) * DMODEL + kc + c4);
            As[c4+0][r] = v.x; As[c4+1][r] = v.y; As[c4+2][r] = v.z; As[c4+3][r] = v.w;
            int rb = id >> 4, cb = (id & 15) << 2;
            *(float4*)&Bs[rb][cb] = *(const float4*)(Bw + (long)(kc + rb) * 512 + n0 + cb);
        }
        __syncthreads();
        #pragma unroll
        for (int kk = 0; kk < 32; ++kk) {
            float4 a4 = *(const float4*)&As[kk][ty << 2];
            float4 b4 = *(const float4*)&Bs[kk][tx << 2];
            float av[4] = {a4.x, a4.y, a4.z, a4.w};
            float bv[4] = {b4.x, b4.y, b4.z, b4.w};
            #pragma unroll
            for (int i = 0; i < 4; ++i)
                #pragma unroll
                for (int j = 0; j < 4; ++j)
                    acc[i][j] = fmaf(av[i], bv[j], acc[i][j]);
        }
        __syncthreads();
    }
    #pragma unroll
    for (int i = 0; i < 4; ++i) {
        int row = m0 + (ty << 2) + i, col = n0 + (tx << 2);
        float4 v4; v4.x = acc[i][0]; v4.y = acc[i][1]; v4.z = acc[i][2]; v4.w = acc[i][3];
        *(float4*)(C + (long)row * 512 + col) = v4;
    }
}

// ---------------------------------------------------------------------------
// Build wcombT bf16 for ALL (br,l): o[bl][n][k];  bl = blockIdx.y (12).
//  n<256: sum_r Wx[k][r]*Wdt[r][n];  256..287: Wx[k][8+(n-256)];  288..319: 0
// ---------------------------------------------------------------------------
__global__ __launch_bounds__(256) void prepC_k(
    const float* __restrict__ Wx, const float* __restrict__ Wdt,
    unsigned short* __restrict__ o)
{
    const int n = blockIdx.x, bl = blockIdx.y;
    const int k = threadIdx.x;
    const float* WxP = Wx + (long)bl * DINNER * 40;
    float v;
    if (n < 256) {
        const float* WdtP = Wdt + (long)bl * DTRANK * DINNER;
        float s = 0.f;
        #pragma unroll
        for (int r = 0; r < 8; ++r) s = fmaf(WxP[k * 40 + r], WdtP[r * DINNER + n], s);
        v = s;
    } else if (n < 288) {
        v = WxP[k * 40 + 8 + (n - 256)];
    } else {
        v = 0.f;
    }
    o[(long)bl * NWB * DINNER + (long)n * DINNER + k] = f2b(v);
}

// ---------------------------------------------------------------------------
// fp32 input projection (K=32): h_bf = bf16(x @ W_ip + b_ip).
// ---------------------------------------------------------------------------
__global__ __launch_bounds__(256) void proj_k(
    const float* __restrict__ A0, const float* __restrict__ A1,
    const float* __restrict__ A2, const float* __restrict__ A3,
    const float* __restrict__ Bw, const float* __restrict__ bias,
    unsigned short* __restrict__ Cb)
{
    const int br = blockIdx.z;
    const float* A = (br == 1) ? A1 : (br == 2) ? A2 : (br == 3) ? A3 : A0;
    Bw   += (long)br * DIN * DMODEL;
    bias += (long)br * DMODEL;
    Cb   += (long)br * BT * DMODEL;
    const int m0 = blockIdx.x * 64, n0 = blockIdx.y * 64;
    __shared__ float As[32][68];
    __shared__ float Bs[32][68];
    const int tid = threadIdx.x;
    const int tx = tid & 15, ty = tid >> 4;
    float acc[4][4] = {};
    {
        #pragma unroll
        for (int it = 0; it < 2; ++it) {
            int id = tid + it * 256;
            int r = id >> 3, c4 = (id & 7) << 2;
            float4 v = *(const float4*)(A + (long)(m0 + r) * DIN + c4);
            As[c4+0][r] = v.x; As[c4+1][r] = v.y; As[c4+2][r] = v.z; As[c4+3][r] = v.w;
            int rb = id >> 4, cb = (id & 15) << 2;
            *(float4*)&Bs[rb][cb] = *(const float4*)(Bw + (long)rb * DMODEL + n0 + cb);
        }
        __syncthreads();
        #pragma unroll
        for (int kk = 0; kk < 32; ++kk) {
            float4 a4 = *(const float4*)&As[kk][ty << 2];
            float4 b4 = *(const float4*)&Bs[kk][tx << 2];
            float av[4] = {a4.x, a4.y, a4.z, a4.w};
            float bv[4] = {b4.x, b4.y, b4.z, b4.w};
            #pragma unroll
            for (int i = 0; i < 4; ++i)
                #pragma unroll
                for (int j = 0; j < 4; ++j)
                    acc[i][j] = fmaf(av[i], bv[j], acc[i][j]);
        }
    }
    const int col = n0 + (tx << 2);
    float bs[4];
    #pragma unroll
    for (int j = 0; j < 4; ++j) bs[j] = bias[col + j];
    #pragma unroll
    for (int i = 0; i < 4; ++i) {
        const int row = m0 + (ty << 2) + i;
        #pragma unroll
        for (int j = 0; j < 4; ++j)
            Cb[(long)row * DMODEL + col + j] = f2b(acc[i][j] + bs[j]);
    }
}

// ---------------------------------------------------------------------------
// Depthwise causal conv (4 taps) + bias + silu: bf16 in -> bf16 out.
// ---------------------------------------------------------------------------
__global__ __launch_bounds__(256) void conv_k(
    const unsigned short* __restrict__ xp, const float* __restrict__ cw,
    const float* __restrict__ cb, unsigned short* __restrict__ xcb, int layer)
{
    const int br = blockIdx.y;
    const long base = (long)br * BT * DINNER;
    const int idx = blockIdx.x * 256 + threadIdx.x;
    const int d = idx & (DINNER - 1);
    const int row = idx >> 8;
    const int t = row & (Tk - 1);
    const float4 w4 = *(const float4*)(cw + ((long)(br * NLAY + layer) * DINNER + d) * 4);
    const float wv[4] = {w4.x, w4.y, w4.z, w4.w};
    float acc = cb[(br * NLAY + layer) * DINNER + d];
    const unsigned short* xpb = xp + base + idx;
    #pragma unroll
    for (int k = 0; k < 4; ++k) {
        int tt = t + k - 3;
        if (tt >= 0) acc = fmaf(b2f(xpb[(long)(k - 3) * DINNER]), wv[k], acc);
    }
    xcb[base + idx] = f2b(siluf(acc));
}

// ---------------------------------------------------------------------------
// Scan pass 1: per-chunk local recurrence from h=0 -> record (h_end[16], sumdt).
// ---------------------------------------------------------------------------
__global__ __launch_bounds__(256) void scan1_k(
    const float* __restrict__ dtb, const unsigned short* __restrict__ xcb,
    const float* __restrict__ bcb, const float* __restrict__ Alog,
    float* __restrict__ recbuf, int layer)
{
    const int c = blockIdx.x, b = blockIdx.y, br = blockIdx.z;
    const int d = threadIdx.x;
    const float* Ap = Alog + ((long)(br * NLAY + layer) * DINNER + d) * DSTATE;
    float Aa[16];
    bool pw = true;
    #pragma unroll
    for (int s = 0; s < 16; ++s) {
        Aa[s] = -__expf(Ap[s]);
        pw = pw && (fabsf(Aa[s] + (float)(s + 1)) < 1e-3f);
    }
    const long rbase = (long)br * BT + (long)b * Tk + (long)c * LCH;
    const float* dtp = dtb + rbase * DINNER + d;
    const unsigned short* xcp = xcb + rbase * DINNER + d;
    __shared__ float bcs[LCH * 32];
    {
        const float4* g = (const float4*)(bcb + rbase * 32);
        float4* l = (float4*)bcs;
        l[d] = g[d]; l[d + 256] = g[d + 256];
    }
    float dtc[UF], xcc[UF];
    #pragma unroll
    for (int u = 0; u < UF; ++u) {
        dtc[u] = dtp[(long)u * DINNER];
        xcc[u] = b2f(xcp[(long)u * DINNER]);
    }
    __syncthreads();
    float h[16];
    #pragma unroll
    for (int s = 0; s < 16; ++s) h[s] = 0.f;
    float sumdt = 0.f;
    for (int base = 0; base < LCH; base += UF) {
        const int nb = (base + UF < LCH) ? base + UF : base;
        float dtn[UF], xcn[UF];
        #pragma unroll
        for (int u = 0; u < UF; ++u) {
            dtn[u] = dtp[(long)(nb + u) * DINNER];
            xcn[u] = b2f(xcp[(long)(nb + u) * DINNER]);
        }
        #pragma unroll
        for (int u = 0; u < UF; ++u) {
            const int t = base + u;
            const float dtv = dtc[u];
            const float dtxc = dtv * xcc[u];
            sumdt += dtv;
            float dA[16];
            if (pw) dA_pow(__expf(-dtv), dA);
            else    dA_exp(dtv, Aa, dA);
            const float* bcT = bcs + t * 32;
            #pragma unroll
            for (int s = 0; s < 16; ++s)
                h[s] = fmaf(dA[s], h[s], dtxc * bcT[s]);
        }
        #pragma unroll
        for (int u = 0; u < UF; ++u) { dtc[u] = dtn[u]; xcc[u] = xcn[u]; }
    }
    float* sb = recbuf + (((long)(br * 4 + b) * (NCH - 1) + c) * 17) * 256 + d;
    #pragma unroll
    for (int s = 0; s < 16; ++s) sb[s * 256] = h[s];
    sb[16 * 256] = sumdt;
}

// ---------------------------------------------------------------------------
// Scan pass 3: fold preceding records into carry (software-pipelined), then
// local recurrence; yz = (y + Dp*xc)*silu(z) -> bf16.
// ---------------------------------------------------------------------------
__global__ __launch_bounds__(256) void scan3_k(
    const float* __restrict__ dtb, const unsigned short* __restrict__ xcb,
    const float* __restrict__ bcb, const float* __restrict__ zb,
    const float* __restrict__ Alog, const float* __restrict__ Dpar,
    const float* __restrict__ recbuf, unsigned short* __restrict__ yzb, int layer)
{
    const int c = blockIdx.x, b = blockIdx.y, br = blockIdx.z;
    const int d = threadIdx.x;
    const float* Ap = Alog + ((long)(br * NLAY + layer) * DINNER + d) * DSTATE;
    float Aa[16];
    bool pw = true;
    #pragma unroll
    for (int s = 0; s < 16; ++s) {
        Aa[s] = -__expf(Ap[s]);
        pw = pw && (fabsf(Aa[s] + (float)(s + 1)) < 1e-3f);
    }
    // ---- carry fold (records 0..c-1), prefetch-pipelined ----
    float h[16];
    #pragma unroll
    for (int s = 0; s < 16; ++s) h[s] = 0.f;
    if (c > 0) {
        const float* recB = recbuf + ((long)(br * 4 + b) * (NCH - 1)) * 17 * 256 + d;
        float rh[16], rs;
        #pragma unroll
        for (int s = 0; s < 16; ++s) rh[s] = recB[s * 256];
        rs = recB[16 * 256];
        for (int cc = 0; cc < c; ++cc) {
            float nh[16], ns = 0.f;
            if (cc + 1 < c) {
                const float* r2 = recB + (long)(cc + 1) * 17 * 256;
                #pragma unroll
                for (int s = 0; s < 16; ++s) nh[s] = r2[s * 256];
                ns = r2[16 * 256];
            } else {
                #pragma unroll
                for (int s = 0; s < 16; ++s) nh[s] = 0.f;
            }
            float P[16];
            if (pw) dA_pow(__expf(-rs), P);
            else    dA_exp(rs, Aa, P);
            #pragma unroll
            for (int s = 0; s < 16; ++s) h[s] = fmaf(h[s], P[s], rh[s]);
            #pragma unroll
            for (int s = 0; s < 16; ++s) rh[s] = nh[s];
            rs = ns;
        }
    }
    // ---- local chunk from carry ----
    const float Dp = Dpar[(br * NLAY + layer) * DINNER + d];
    const long rbase = (long)br * BT + (long)b * Tk + (long)c * LCH;
    const float* dtp = dtb + rbase * DINNER + d;
    const unsigned short* xcp = xcb + rbase * DINNER + d;
    const float* zp  = zb  + rbase * DINNER + d;
    unsigned short* yp = yzb + rbase * DINNER + d;
    __shared__ float bcs[LCH * 32];
    {
        const float4* g = (const float4*)(bcb + rbase * 32);
        float4* l = (float4*)bcs;
        l[d] = g[d]; l[d + 256] = g[d + 256];
    }
    float dtc[UF], xcc[UF], zc[UF];
    #pragma unroll
    for (int u = 0; u < UF; ++u) {
        dtc[u] = dtp[(long)u * DINNER];
        xcc[u] = b2f(xcp[(long)u * DINNER]);
        zc[u]  = zp[(long)u * DINNER];
    }
    __syncthreads();
    for (int base = 0; base < LCH; base += UF) {
        const int nb = (base + UF < LCH) ? base + UF : base;
        float dtn[UF], xcn[UF], zn[UF];
        #pragma unroll
        for (int u = 0; u < UF; ++u) {
            dtn[u] = dtp[(long)(nb + u) * DINNER];
            xcn[u] = b2f(xcp[(long)(nb + u) * DINNER]);
            zn[u]  = zp[(long)(nb + u) * DINNER];
        }
        #pragma unroll
        for (int u = 0; u < UF; ++u) {
            const int t = base + u;
            const float dtv = dtc[u], xcv = xcc[u];
            const float dtxc = dtv * xcv;
            float dA[16];
            if (pw) dA_pow(__expf(-dtv), dA);
            else    dA_exp(dtv, Aa, dA);
            const float* bcT = bcs + t * 32;
            #pragma unroll
            for (int s = 0; s < 16; ++s)
                h[s] = fmaf(dA[s], h[s], dtxc * bcT[s]);
            float y0 = 0.f, y1 = 0.f, y2 = 0.f, y3 = 0.f;
            #pragma unroll
            for (int s = 0; s < 16; s += 4) {
                y0 = fmaf(h[s+0], bcT[16+s+0], y0);
                y1 = fmaf(h[s+1], bcT[16+s+1], y1);
                y2 = fmaf(h[s+2], bcT[16+s+2], y2);
                y3 = fmaf(h[s+3], bcT[16+s+3], y3);
            }
            const float y = (y0 + y1) + (y2 + y3) + Dp * xcv;
            yp[(long)t * DINNER] = f2b(y * zc[u]);
        }
        #pragma unroll
        for (int u = 0; u < UF; ++u) { dtc[u] = dtn[u]; xcc[u] = xcn[u]; zc[u] = zn[u]; }
    }
}

// ---------------------------------------------------------------------------
// mean over T then @ W_op + b_op -> z_t directly into d_out[0..1023].
// ---------------------------------------------------------------------------
__global__ __launch_bounds__(128) void meanop_k(
    const float* __restrict__ hbuf, const float* __restrict__ Wop,
    const float* __restrict__ bop, float* __restrict__ outzt)
{
    const int br = blockIdx.x >> 2, b = blockIdx.x & 3;
    const int tid = threadIdx.x;
    const float* hp = hbuf + ((long)br * BT + (long)b * Tk) * DMODEL + tid;
    float s = 0.f;
    for (int t = 0; t < Tk; ++t) s += hp[(long)t * DMODEL];
    __shared__ float hm[DMODEL];
    hm[tid] = s * (1.0f / Tk);
    __syncthreads();
    if (tid < EMBEDk) {
        float acc = bop[br * EMBEDk + tid];
        for (int k = 0; k < DMODEL; ++k)
            acc = fmaf(hm[k], Wop[(long)br * DMODEL * EMBEDk + k * EMBEDk + tid], acc);
        outzt[br * (Bk * EMBEDk) + b * EMBEDk + tid] = acc;
    }
}

// ---------------------------------------------------------------------------
// Lorentz epilogue.
// ---------------------------------------------------------------------------
__global__ __launch_bounds__(64) void final_k(
    const float* __restrict__ zt, float* __restrict__ out, const float* __restrict__ eff)
{
    const float es = tanhf(eff[0]);
    __shared__ float us[NBR][Bk][EMBEDk];
    const int t = threadIdx.x;
    if (t < 16) {
        const int br = t >> 2, b = t & 3;
        const float* z = zt + br * (Bk * EMBEDk) + b * EMBEDk;
        float n2 = 0.f;
        for (int e = 0; e < EMBEDk; ++e) { float v = z[e] * es; n2 = fmaf(v, v, n2); }
        const float n  = sqrtf(n2);
        const float nc = fminf(fmaxf(n, EPSF), MAXNF);
        const float sc = nc / fmaxf(n, EPSF);
        const float sh = sinhf(nc) / nc;
        const float fac = es * sc * sh;
        float* zh = out + 1024 + br * (Bk * (EMBEDk + 1)) + b * (EMBEDk + 1);
        float sp2 = 0.f;
        for (int e = 0; e < EMBEDk; ++e) {
            float spv = z[e] * fac;
            sp2 = fmaf(spv, spv, sp2);
            zh[1 + e] = spv;
            us[br][b][e] = spv;
        }
        const float t0 = sqrtf(1.f + sp2);
        zh[0] = t0;
        const float dd  = acoshf(fmaxf(t0, 1.f + EPSF));
        const float spn = fmaxf(sqrtf(sp2), EPSF);
        const float rr  = dd / spn;
        for (int e = 0; e < EMBEDk; ++e) us[br][b][e] *= rr;
    }
    __syncthreads();
    if (t < 4) {
        const int b = t;
        float ct[EMBEDk];
        float* cto = out + 2064 + b * EMBEDk;
        for (int e = 0; e < EMBEDk; ++e) {
            float v = us[0][b][e] + us[1][b][e] + us[2][b][e] + us[3][b][e];
            ct[e] = v; cto[e] = v;
        }
        float n2 = 0.f;
        for (int e = 0; e < EMBEDk; ++e) { float v = ct[e] * es; n2 = fmaf(v, v, n2); }
        const float n  = sqrtf(n2);
        const float nc = fminf(fmaxf(n, EPSF), MAXNF);
        const float sc = nc / fmaxf(n, EPSF);
        const float sh = sinhf(nc) / nc;
        const float fac = es * sc * sh;
        float* ch = out + 2320 + b * (EMBEDk + 1);
        float sp2 = 0.f;
        for (int e = 0; e < EMBEDk; ++e) {
            float spv = ct[e] * fac;
            sp2 = fmaf(spv, spv, sp2);
            ch[1 + e] = spv;
        }
        ch[0] = sqrtf(1.f + sp2);
    }
}

extern "C" void kernel_launch(void* const* d_in, const int* in_sizes, int n_in,
                              void* d_out, int out_size, void* d_ws, size_t ws_size,
                              hipStream_t stream)
{
    const float* X0 = (const float*)d_in[0];
    const float* X1 = (const float*)d_in[1];
    const float* X2 = (const float*)d_in[2];
    const float* X3 = (const float*)d_in[3];
    const float* W_ip   = (const float*)d_in[4];
    const float* b_ip   = (const float*)d_in[5];
    const float* W_in   = (const float*)d_in[6];
    const float* conv_w = (const float*)d_in[7];
    const float* conv_b = (const float*)d_in[8];
    const float* W_x    = (const float*)d_in[9];
    const float* W_dt   = (const float*)d_in[10];
    const float* b_dt   = (const float*)d_in[11];
    const float* A_log  = (const float*)d_in[12];
    const float* D_par  = (const float*)d_in[13];
    const float* W_out  = (const float*)d_in[14];
    const float* W_op   = (const float*)d_in[15];
    const float* b_op   = (const float*)d_in[16];
    const float* eff    = (const float*)d_in[17];
    float* out = (float*)d_out;
    float* ws  = (float*)d_ws;

    // ---- workspace (no aliasing; ~65 MB) ----
    float* buf_z  = ws;                                   // 4.19M f32
    float* buf_dt = buf_z  + (long)NBR * BT * DINNER;     // 4.19M f32
    float* buf_bc = buf_dt + (long)NBR * BT * DINNER;     // 0.52M f32
    float* buf_h  = buf_bc + (long)NBR * BT * 32;         // 2.10M f32 (final h)
    float* recbuf = buf_h  + (long)NBR * BT * DMODEL;     // 1.04M f32
    float* Wtmp   = recbuf + (long)16 * (NCH - 1) * 17 * 256;  // 8*256*512 f32
    unsigned short* h_bf  = (unsigned short*)(Wtmp + (long)8 * DINNER * 512);
    unsigned short* xp_bf = h_bf  + (long)NBR * BT * DMODEL;   // 4.19M u16
    unsigned short* xc_bf = xp_bf + (long)NBR * BT * DINNER;   // 4.19M u16
    unsigned short* yz_bf = xc_bf + (long)NBR * BT * DINNER;   // 4.19M u16
    unsigned short* Win0T = yz_bf + (long)NBR * BT * DINNER;   // 4*512*128 u16
    unsigned short* WfT   = Win0T + (long)NBR * 512 * DMODEL;  // 8*512*256 u16
    unsigned short* WcT   = WfT   + (long)8 * 512 * DINNER;    // 12*320*256 u16
    unsigned short* Wo2T  = WcT   + (long)NBR * NLAY * NWB * DINNER; // 4*128*256 u16

    // ---- weight prep (once) ----
    // Win_0^T -> bf16 [512][128]
    prepT_k<<<dim3(8, 2, NBR), 256, 0, stream>>>(
        W_in, Win0T, DMODEL, 512, (long)NLAY * DMODEL * 512, (long)512 * DMODEL);
    // Wtmp[p][br] = Wout_p @ Win_{p+1}  (fp32, [256][512])
    sgemmW_k<<<dim3(4, 8, 8), 256, 0, stream>>>(W_out, W_in, Wtmp);
    // WfT = Wtmp^T -> bf16 [512][256]
    prepT_k<<<dim3(8, 4, 8), 256, 0, stream>>>(
        Wtmp, WfT, DINNER, 512, (long)DINNER * 512, (long)512 * DINNER);
    // wcombT all (br,l)
    prepC_k<<<dim3(NWB, NBR * NLAY), 256, 0, stream>>>(W_x, W_dt, WcT);
    // Wout_2^T -> bf16 [128][256]
    prepT_k<<<dim3(2, 4, NBR), 256, 0, stream>>>(
        W_out + (long)2 * DINNER * DMODEL, Wo2T, DINNER, DMODEL,
        (long)NLAY * DINNER * DMODEL, (long)DMODEL * DINNER);

    // ---- input projection: h_bf = bf16(x @ W_ip + b_ip) ----
    proj_k<<<dim3(BT / 64, DMODEL / 64, NBR), 256, 0, stream>>>(
        X0, X1, X2, X3, W_ip, b_ip, h_bf);

    for (int l = 0; l < NLAY; ++l) {
        // xz: l==0: h_bf @ Win_0 (K=128); else: yz_bf @ (Wout_{l-1}·Win_l) (K=256)
        if (l == 0) {
            bgemm_k<0><<<dim3(BT / 64, 8, NBR), 256, 0, stream>>>(
                h_bf, (long)BT * DMODEL, DMODEL,
                Win0T, (long)512 * DMODEL,
                nullptr, 0, buf_z, (long)BT * DINNER,
                xp_bf, (long)BT * DINNER, nullptr, 0);
        } else {
            bgemm_k<0><<<dim3(BT / 64, 8, NBR), 256, 0, stream>>>(
                yz_bf, (long)BT * DINNER, DINNER,
                WfT + (long)(l - 1) * 4 * 512 * DINNER, (long)512 * DINNER,
                nullptr, 0, buf_z, (long)BT * DINNER,
                xp_bf, (long)BT * DINNER, nullptr, 0);
        }
        // depthwise conv + silu (bf16 -> bf16)
        conv_k<<<dim3((BT * DINNER) / 256, NBR), 256, 0, stream>>>(
            xp_bf, conv_w, conv_b, xc_bf, l);
        // dt = softplus(xc @ wc + b_dt); bc = xc @ wcBC
        bgemm_k<3><<<dim3(BT / 64, NWB / 64, NBR), 256, 0, stream>>>(
            xc_bf, (long)BT * DINNER, DINNER,
            WcT + (long)l * NWB * DINNER, (long)NLAY * NWB * DINNER,
            buf_dt, (long)BT * DINNER, buf_bc, (long)BT * 32,
            nullptr, 0, b_dt + l * DINNER, (long)NLAY * DINNER);
        // chunked scan: records -> (fold + local + y) -> yz bf16
        scan1_k<<<dim3(NCH - 1, Bk, NBR), 256, 0, stream>>>(
            buf_dt, xc_bf, buf_bc, A_log, recbuf, l);
        scan3_k<<<dim3(NCH, Bk, NBR), 256, 0, stream>>>(
            buf_dt, xc_bf, buf_bc, buf_z, A_log, D_par, recbuf, yz_bf, l);
        // final layer only: h = yz @ Wout_2 (fp32 out for meanop)
        if (l == NLAY - 1) {
            bgemm_k<1><<<dim3(BT / 64, DMODEL / 64, NBR), 256, 0, stream>>>(
                yz_bf, (long)BT * DINNER, DINNER,
                Wo2T, (long)DMODEL * DINNER,
                buf_h, (long)BT * DMODEL, nullptr, 0,
                nullptr, 0, nullptr, 0);
        }
    }

    meanop_k<<<16, 128, 0, stream>>>(buf_h, W_op, b_op, out);
    final_k<<<1, 64, 0, stream>>>(out, out, eff);
}